// Round 3
// baseline (1359.746 us; speedup 1.0000x reference)
//
#include <hip/hip_runtime.h>

// SP_DNN: two fused 1->256->256->256->256 MLPs (sin activations) + strided rowwise dot.
// fp16 MFMA (16x16x32), fp32 accumulate.
//
// R3: row-split + K-stagger + interleaved prefetch (R2 lesson: occupancy was
// not binding; pipes MFMA/LDS/L2/VALU each ~30% and phase-serialized).
//  - 8 waves = 2 row-groups x 4 channel-groups: wave owns 32 rows x 64 ch.
//    B-LDS traffic halves (each wave reads 16KB not 32KB per layer); waves
//    w and w+4 load identical A fragments (L1 sharing).
//  - Per-wave K-stagger (g0 = wv*2): co-resident waves start at different
//    K-groups -> A-load / MFMA / LDS bursts desynchronize (anti-convoy).
//  - bfr double-buffered across g; afr reloaded interleaved inside the MFMA
//    nest (after last use per fragment) -> L2 latency hidden, zero extra regs.
//  - s_setprio(1) around the MFMA cluster.
// Register budget: ~60 VGPR + 64 AGPR (acc 32 + xacc 32) <= 128 -> 4 waves/SIMD.

typedef _Float16 f16x8 __attribute__((ext_vector_type(8)));
typedef _Float16 f16x4 __attribute__((ext_vector_type(4)));
typedef float f32x4 __attribute__((ext_vector_type(4)));

// Swizzled hbuf byte offset: row m (0..63, 512 B stride), kbyte in [0,512).
// 16B unit index XORed with (m&7): any 8-lane chunk of a B-read covers all
// 32 banks exactly once; writeback/layer0 patterns are <=2-way (free).
__device__ __forceinline__ int hswz(int m, int kbyte) {
    return m * 512 + ((((kbyte >> 4) ^ (m & 7)) & 31) << 4) + (kbyte & 15);
}

// ---------------------------------------------------------------------------
// Prepack: 6 matrices W[k][n] (256x256 f32, k-major) -> fp16 A-fragment-major:
// idx = ((((c*2+ks)*16 + nhi)*4 + quad)*16 + ln)*8 + j
//   n = nhi*16+ln, k = c*64 + ks*32 + quad*8 + j
// ---------------------------------------------------------------------------
__global__ void prepack(const float* __restrict__ xW1, const float* __restrict__ xW2,
                        const float* __restrict__ xW3, const float* __restrict__ tW1,
                        const float* __restrict__ tW2, const float* __restrict__ tW3,
                        _Float16* __restrict__ dst)
{
    int g = blockIdx.x * 256 + threadIdx.x;   // 6*65536 threads exactly
    int L = g >> 16;
    int r = g & 65535;
    int j    = r & 7;
    int ln   = (r >> 3) & 15;
    int quad = (r >> 7) & 3;
    int nhi  = (r >> 9) & 15;
    int ks   = (r >> 13) & 1;
    int c    = (r >> 14) & 3;
    const float* W;
    switch (L) {
        case 0: W = xW1; break;
        case 1: W = xW2; break;
        case 2: W = xW3; break;
        case 3: W = tW1; break;
        case 4: W = tW2; break;
        default: W = tW3; break;
    }
    int n = nhi * 16 + ln;
    int k = c * 64 + ks * 32 + quad * 8 + j;
    dst[g] = (_Float16)W[k * 256 + n];
}

// ---------------------------------------------------------------------------
// Main fused kernel. Block = 512 threads (8 waves), tile = 64 rows.
// wave = rg*4 + wv:  rg in {0,1} = row-group (rows rg*32..rg*32+31),
//                    wv in 0..3  = channel-group (channels wv*64..wv*64+63).
// ---------------------------------------------------------------------------

__device__ __forceinline__ void layer0_scalar(
    const float* __restrict__ x, int row0, int sel,
    const float* __restrict__ W0, const float* __restrict__ b0,
    _Float16* __restrict__ hb, int tid)
{
    int m = tid >> 3;        // 64 rows, 8 threads per row
    int q = tid & 7;         // each thread does 32 of the 256 channels
    float xv = x[(row0 + m) * 2 + sel];
#pragma unroll
    for (int g = 0; g < 4; ++g) {
        int n0 = q * 32 + g * 8;
        f16x8 hv;
#pragma unroll
        for (int e = 0; e < 8; ++e) {
            float z = fmaf(xv, W0[n0 + e], b0[n0 + e]);
            hv[e] = (_Float16)__sinf(z);
        }
        *(f16x8*)((char*)hb + hswz(m, n0 * 2)) = hv;
    }
}

// One 256->256 layer over a SINGLE shared activation buffer.
// Wave computes its 32 rows x 64 channels. K-loop staggered by g0 = wv*2.
// acc[i][jj]: i = channel frag (4 x 16ch), jj = row frag (2 x 16 rows).
template<bool WRITE_H>
__device__ __forceinline__ void gemm_layer(
    const _Float16* __restrict__ Wl,     // packed layer base (65536 elems)
    const float* __restrict__ bias,      // 256 f32 (only used if WRITE_H)
    _Float16* __restrict__ hb,           // activation buffer (read, then write)
    f32x4 acc[4][2],
    int lane, int ln, int quad, int wv, int rg)
{
    f32x4 zero = {0.f, 0.f, 0.f, 0.f};
#pragma unroll
    for (int i = 0; i < 4; ++i)
#pragma unroll
        for (int jj = 0; jj < 2; ++jj)
            acc[i][jj] = zero;

    // A fragment (g, i): Wl + (g*16 + wv*4 + i)*512 + lane*8
    const _Float16* abase = Wl + wv * 2048 + lane * 8;
    const int g0 = wv * 2;               // per-wave K-stagger (anti-convoy)
    const int mrow0 = rg * 32 + ln;      // jj=0 row; jj=1 adds 16

    f16x8 afr[4];
    f16x8 bfr[2][2];
    {
        int g = g0;
#pragma unroll
        for (int i = 0; i < 4; ++i)
            afr[i] = *(const f16x8*)(abase + g * 8192 + i * 512);
#pragma unroll
        for (int jj = 0; jj < 2; ++jj)
            bfr[0][jj] = *(const f16x8*)((const char*)hb +
                             hswz(mrow0 + 16 * jj, g * 64 + quad * 16));
    }

#pragma unroll
    for (int t = 0; t < 8; ++t) {
        const int gn = (g0 + t + 1) & 7;
        if (t < 7) {                      // double-buffered B prefetch
#pragma unroll
            for (int jj = 0; jj < 2; ++jj)
                bfr[(t + 1) & 1][jj] = *(const f16x8*)((const char*)hb +
                                 hswz(mrow0 + 16 * jj, gn * 64 + quad * 16));
        }
        __builtin_amdgcn_s_setprio(1);
#pragma unroll
        for (int i = 0; i < 4; ++i) {
            acc[i][0] = __builtin_amdgcn_mfma_f32_16x16x32_f16(
                afr[i], bfr[t & 1][0], acc[i][0], 0, 0, 0);
            acc[i][1] = __builtin_amdgcn_mfma_f32_16x16x32_f16(
                afr[i], bfr[t & 1][1], acc[i][1], 0, 0, 0);
            if (t < 7)                    // reload afr[i] right after last use
                afr[i] = *(const f16x8*)(abase + gn * 8192 + i * 512);
        }
        __builtin_amdgcn_s_setprio(0);
    }

    __syncthreads();   // every wave's B reads of hb are complete

    if (WRITE_H) {
#pragma unroll
        for (int i = 0; i < 4; ++i) {
            int nb = wv * 64 + 16 * i + quad * 4;            // 4 consecutive channels
            f32x4 bv = *(const f32x4*)&bias[nb];
#pragma unroll
            for (int jj = 0; jj < 2; ++jj) {
                f16x4 hv;
                hv[0] = (_Float16)__sinf(acc[i][jj][0] + bv[0]);
                hv[1] = (_Float16)__sinf(acc[i][jj][1] + bv[1]);
                hv[2] = (_Float16)__sinf(acc[i][jj][2] + bv[2]);
                hv[3] = (_Float16)__sinf(acc[i][jj][3] + bv[3]);
                *(f16x4*)((char*)hb + hswz(mrow0 + 16 * jj, nb * 2)) = hv;
            }
        }
        __syncthreads();   // writes visible before next layer's B reads
    }
}

__global__ __launch_bounds__(512, 4)
void mlp_fused(const float* __restrict__ x,
               const float* __restrict__ xW0, const float* __restrict__ xb0,
               const float* __restrict__ xb1, const float* __restrict__ xb2,
               const float* __restrict__ xb3,
               const float* __restrict__ tW0, const float* __restrict__ tb0,
               const float* __restrict__ tb1, const float* __restrict__ tb2,
               const float* __restrict__ tb3,
               const _Float16* __restrict__ Wp,
               float* __restrict__ out)
{
    __shared__ __align__(16) _Float16 hbuf[64 * 256];   // single 32 KB buffer

    const int tid = threadIdx.x;
    const int lane = tid & 63;
    const int wave = tid >> 6;       // 0..7
    const int ln = lane & 15;
    const int quad = lane >> 4;
    const int wv = wave & 3;         // channel group
    const int rg = wave >> 2;        // row group
    const int row0 = blockIdx.x * 64;

    f32x4 xacc[4][2], tacc[4][2];

    // ----- x-MLP -----  (single buffer; read-barrier-write-barrier per layer)
    layer0_scalar(x, row0, 0, xW0, xb0, hbuf, tid);
    __syncthreads();
    gemm_layer<true >(Wp + 0 * 65536, xb1, hbuf, tacc, lane, ln, quad, wv, rg);
    gemm_layer<true >(Wp + 1 * 65536, xb2, hbuf, tacc, lane, ln, quad, wv, rg);
    gemm_layer<false>(Wp + 2 * 65536, nullptr, hbuf, xacc, lane, ln, quad, wv, rg);
    // xacc = x-MLP layer3 pre-bias output, kept in registers.
    // gemm_layer<false> ended with a barrier after its reads -> hbuf is dead.

    // ----- t-MLP -----
    layer0_scalar(x, row0, 1, tW0, tb0, hbuf, tid);
    __syncthreads();
    gemm_layer<true >(Wp + 3 * 65536, tb1, hbuf, tacc, lane, ln, quad, wv, rg);
    gemm_layer<true >(Wp + 4 * 65536, tb2, hbuf, tacc, lane, ln, quad, wv, rg);
    gemm_layer<false>(Wp + 5 * 65536, nullptr, hbuf, tacc, lane, ln, quad, wv, rg);

    // ----- combine: even/odd strided dot, fp32 -----
    // Channel parity == f32x4 reg-index parity (nb is a multiple of 4).
    float ev[2] = {0.f, 0.f};
    float od[2] = {0.f, 0.f};
#pragma unroll
    for (int i = 0; i < 4; ++i) {
        int nb = wv * 64 + 16 * i + quad * 4;
        f32x4 xb = *(const f32x4*)&xb3[nb];
        f32x4 tb = *(const f32x4*)&tb3[nb];
#pragma unroll
        for (int jj = 0; jj < 2; ++jj) {
            float a0 = xacc[i][jj][0] + xb[0], c0 = tacc[i][jj][0] + tb[0];
            float a1 = xacc[i][jj][1] + xb[1], c1 = tacc[i][jj][1] + tb[1];
            float a2 = xacc[i][jj][2] + xb[2], c2 = tacc[i][jj][2] + tb[2];
            float a3 = xacc[i][jj][3] + xb[3], c3 = tacc[i][jj][3] + tb[3];
            ev[jj] += a0 * c0 + a2 * c2;
            od[jj] += a1 * c1 + a3 * c3;
        }
    }
#pragma unroll
    for (int jj = 0; jj < 2; ++jj) {         // reduce over the 4 quads
        ev[jj] += __shfl_xor(ev[jj], 16, 64);
        ev[jj] += __shfl_xor(ev[jj], 32, 64);
        od[jj] += __shfl_xor(od[jj], 16, 64);
        od[jj] += __shfl_xor(od[jj], 32, 64);
    }

    // Per-wave partials: wave holds rows rg*32+16jj+ln (jj=0,1), summed over
    // its 64 channels. Need sum over the 4 channel-groups (wv) per row.
    float* red = (float*)hbuf;               // hbuf dead (t-L3 read-barrier passed)
    if (lane < 16) {
#pragma unroll
        for (int jj = 0; jj < 2; ++jj) {
            red[wave * 64 + jj * 32 + ln * 2 + 0] = ev[jj];
            red[wave * 64 + jj * 32 + ln * 2 + 1] = od[jj];
        }
    }
    __syncthreads();
    if (tid < 128) {                         // 1 thread per (row, parity); coalesced
        int p = tid & 1, m = tid >> 1;       // m = 0..63
        int rgo = m >> 5, jj = (m >> 4) & 1, l = m & 15;
        int base = jj * 32 + l * 2 + p;
        float s = 0.f;
#pragma unroll
        for (int w = 0; w < 4; ++w)          // sum the 4 channel-groups
            s += red[(rgo * 4 + w) * 64 + base];
        out[(row0 + m) * 2 + p] = s;
    }
}

// ---------------------------------------------------------------------------
extern "C" void kernel_launch(void* const* d_in, const int* in_sizes, int n_in,
                              void* d_out, int out_size, void* d_ws, size_t ws_size,
                              hipStream_t stream)
{
    const float* x   = (const float*)d_in[0];
    const float* xW0 = (const float*)d_in[1];
    const float* xb0 = (const float*)d_in[2];
    const float* xW1 = (const float*)d_in[3];
    const float* xb1 = (const float*)d_in[4];
    const float* xW2 = (const float*)d_in[5];
    const float* xb2 = (const float*)d_in[6];
    const float* xW3 = (const float*)d_in[7];
    const float* xb3 = (const float*)d_in[8];
    const float* tW0 = (const float*)d_in[9];
    const float* tb0 = (const float*)d_in[10];
    const float* tW1 = (const float*)d_in[11];
    const float* tb1 = (const float*)d_in[12];
    const float* tW2 = (const float*)d_in[13];
    const float* tb2 = (const float*)d_in[14];
    const float* tW3 = (const float*)d_in[15];
    const float* tb3 = (const float*)d_in[16];

    _Float16* Wp = (_Float16*)d_ws;          // 6*65536 fp16 = 768 KB
    const int N = in_sizes[0] / 2;           // 1,000,000 (divisible by 64)

    prepack<<<1536, 256, 0, stream>>>(xW1, xW2, xW3, tW1, tW2, tW3, Wp);
    mlp_fused<<<N / 64, 512, 0, stream>>>(x, xW0, xb0, xb1, xb2, xb3,
                                          tW0, tb0, tb1, tb2, tb3,
                                          Wp, (float*)d_out);
}

// Round 4
// 1274.336 us; speedup vs baseline: 1.0670x; 1.0670x over previous
//
#include <hip/hip_runtime.h>

// SP_DNN: two fused 1->256->256->256->256 MLPs (sin activations) + strided rowwise dot.
// fp16 MFMA (16x16x32), fp32 accumulate.
//
// R4: traffic-optimal R0 geometry (4 waves x 64ch, 4-way B reuse, no A dup)
// with two fixes for the serialized-pipes disease (R2/R3 lessons):
//  - nx (x-MLP output) packed to fp16 (+bias) -> frees 32 regs vs fp32 xacc;
//    total ~165 regs -> 3 waves/SIMD (launch_bounds(256,3)) vs R0's 2.
//  - All activation barriers are raw s_barrier with lgkmcnt(0)-only drain
//    (NOT __syncthreads' vmcnt(0) full drain): global A-fragment loads stay
//    in flight across barriers. Each layer's K-loop tail prefetches the NEXT
//    layer's g=0 A fragments -> L2 latency hides under sin/write phase.

typedef _Float16 f16x8 __attribute__((ext_vector_type(8)));
typedef _Float16 f16x4 __attribute__((ext_vector_type(4)));
typedef float f32x4 __attribute__((ext_vector_type(4)));

// Swizzled hbuf byte offset: row m (0..63, 512 B stride), kbyte in [0,512).
// 16B unit index XORed with (m&7): any 8-lane chunk of a B-read covers all
// 32 banks exactly once; writeback/layer0 patterns are <=2-way (free).
__device__ __forceinline__ int hswz(int m, int kbyte) {
    return m * 512 + ((((kbyte >> 4) ^ (m & 7)) & 31) << 4) + (kbyte & 15);
}

// Raw workgroup barrier that drains LDS ops only; leaves global loads
// (vmcnt) in flight. "memory" clobber pins LDS read/write ordering.
__device__ __forceinline__ void barrier_lds() {
    asm volatile("s_waitcnt lgkmcnt(0)" ::: "memory");
    __builtin_amdgcn_s_barrier();
}

// ---------------------------------------------------------------------------
// Prepack: 6 matrices W[k][n] (256x256 f32, k-major) -> fp16 A-fragment-major:
// idx = ((((c*2+ks)*16 + nhi)*4 + quad)*16 + ln)*8 + j
//   n = nhi*16+ln, k = c*64 + ks*32 + quad*8 + j
// ---------------------------------------------------------------------------
__global__ void prepack(const float* __restrict__ xW1, const float* __restrict__ xW2,
                        const float* __restrict__ xW3, const float* __restrict__ tW1,
                        const float* __restrict__ tW2, const float* __restrict__ tW3,
                        _Float16* __restrict__ dst)
{
    int g = blockIdx.x * 256 + threadIdx.x;   // 6*65536 threads exactly
    int L = g >> 16;
    int r = g & 65535;
    int j    = r & 7;
    int ln   = (r >> 3) & 15;
    int quad = (r >> 7) & 3;
    int nhi  = (r >> 9) & 15;
    int ks   = (r >> 13) & 1;
    int c    = (r >> 14) & 3;
    const float* W;
    switch (L) {
        case 0: W = xW1; break;
        case 1: W = xW2; break;
        case 2: W = xW3; break;
        case 3: W = tW1; break;
        case 4: W = tW2; break;
        default: W = tW3; break;
    }
    int n = nhi * 16 + ln;
    int k = c * 64 + ks * 32 + quad * 8 + j;
    dst[g] = (_Float16)W[k * 256 + n];
}

// ---------------------------------------------------------------------------
// Main fused kernel. Block = 256 threads (4 waves), tile = 64 rows.
// Wave w owns out-channels [w*64, w*64+64).
// ---------------------------------------------------------------------------

__device__ __forceinline__ void layer0_scalar(
    const float* __restrict__ x, int row0, int sel,
    const float* __restrict__ W0, const float* __restrict__ b0,
    _Float16* __restrict__ hb, int tid)
{
    int m = tid >> 2;        // 64 rows, 4 threads per row
    int q = tid & 3;         // each thread does 64 of the 256 channels
    float xv = x[(row0 + m) * 2 + sel];
#pragma unroll
    for (int g = 0; g < 8; ++g) {
        int n0 = q * 64 + g * 8;
        f16x8 hv;
#pragma unroll
        for (int e = 0; e < 8; ++e) {
            float z = fmaf(xv, W0[n0 + e], b0[n0 + e]);
            hv[e] = (_Float16)__sinf(z);
        }
        *(f16x8*)((char*)hb + hswz(m, n0 * 2)) = hv;
    }
}

// One 256->256 layer over a SINGLE shared activation buffer.
// afr is caller-persistent; at entry afr[0] holds THIS layer's g=0 fragments.
// K-loop tail (g=7) prefetches Wnext's g=0 fragments into afr[0] -- they
// stay in flight across the raw barriers (no vmcnt drain).
// D layout: col=lane&15 = batch row m, row=quad*4+r = out channel.
template<bool WRITE_H>
__device__ __forceinline__ void gemm_layer(
    const _Float16* __restrict__ Wl,     // packed layer base (65536 elems)
    const _Float16* __restrict__ Wnext,  // next layer base (nullptr at end)
    const float* __restrict__ bias,      // 256 f32 (only used if WRITE_H)
    _Float16* __restrict__ hb,           // activation buffer (read, then write)
    f32x4 acc[4][4], f16x8 afr[2][4],
    int lane, int ln, int quad, int wave)
{
    f32x4 zero = {0.f, 0.f, 0.f, 0.f};
#pragma unroll
    for (int i = 0; i < 4; ++i)
#pragma unroll
        for (int j = 0; j < 4; ++j)
            acc[i][j] = zero;

    // A fragment (g, i): Wl + g*8192 + wave*2048 + i*512 + lane*8
    const _Float16* abase = Wl + wave * 2048 + lane * 8;

#pragma unroll
    for (int g = 0; g < 8; ++g) {
        if (g < 7) {                      // double-buffered A prefetch
#pragma unroll
            for (int i = 0; i < 4; ++i)
                afr[(g + 1) & 1][i] = *(const f16x8*)(abase + (g + 1) * 8192 + i * 512);
        } else if (Wnext) {               // tail: prefetch NEXT layer's g=0
            const _Float16* nbase = Wnext + wave * 2048 + lane * 8;
#pragma unroll
            for (int i = 0; i < 4; ++i)
                afr[0][i] = *(const f16x8*)(nbase + i * 512);
        }
        f16x8 bfr[4];
#pragma unroll
        for (int j = 0; j < 4; ++j) {    // B: activations, all 64 rows
            bfr[j] = *(const f16x8*)((const char*)hb +
                                     hswz(16 * j + ln, g * 64 + quad * 16));
        }
        __builtin_amdgcn_s_setprio(1);
#pragma unroll
        for (int i = 0; i < 4; ++i)
#pragma unroll
            for (int j = 0; j < 4; ++j)
                acc[i][j] = __builtin_amdgcn_mfma_f32_16x16x32_f16(
                    afr[g & 1][i], bfr[j], acc[i][j], 0, 0, 0);
        __builtin_amdgcn_s_setprio(0);
    }

    barrier_lds();   // all waves' B reads done; A prefetch stays in flight

    if (WRITE_H) {
#pragma unroll
        for (int i = 0; i < 4; ++i) {
            int nb = wave * 64 + 16 * i + quad * 4;          // 4 consecutive channels
            f32x4 bv = *(const f32x4*)&bias[nb];
#pragma unroll
            for (int j = 0; j < 4; ++j) {
                f16x4 hv;
                hv[0] = (_Float16)__sinf(acc[i][j][0] + bv[0]);
                hv[1] = (_Float16)__sinf(acc[i][j][1] + bv[1]);
                hv[2] = (_Float16)__sinf(acc[i][j][2] + bv[2]);
                hv[3] = (_Float16)__sinf(acc[i][j][3] + bv[3]);
                *(f16x4*)((char*)hb + hswz(16 * j + ln, nb * 2)) = hv;
            }
        }
        barrier_lds();   // writes visible before next layer's B reads
    }
}

__global__ __launch_bounds__(256, 3)
void mlp_fused(const float* __restrict__ x,
               const float* __restrict__ xW0, const float* __restrict__ xb0,
               const float* __restrict__ xb1, const float* __restrict__ xb2,
               const float* __restrict__ xb3,
               const float* __restrict__ tW0, const float* __restrict__ tb0,
               const float* __restrict__ tb1, const float* __restrict__ tb2,
               const float* __restrict__ tb3,
               const _Float16* __restrict__ Wp,
               float* __restrict__ out)
{
    __shared__ __align__(16) _Float16 hbuf[64 * 256];   // single 32 KB buffer

    const int tid = threadIdx.x;
    const int lane = tid & 63;
    const int wave = tid >> 6;       // 0..3
    const int ln = lane & 15;
    const int quad = lane >> 4;
    const int row0 = blockIdx.x * 64;

    f32x4 acc[4][4];                 // live GEMM accumulator (64 AGPR)
    f16x4 xnx[4][4];                 // x-MLP output, fp16 packed (32 regs)
    f16x8 afr[2][4];                 // A-fragment double buffer (32 VGPR)

    // Prefetch layer xW1 g=0 fragments; they land during layer0's sin work.
    {
        const _Float16* a0 = Wp + wave * 2048 + lane * 8;
#pragma unroll
        for (int i = 0; i < 4; ++i)
            afr[0][i] = *(const f16x8*)(a0 + i * 512);
    }

    // ----- x-MLP -----
    layer0_scalar(x, row0, 0, xW0, xb0, hbuf, tid);
    barrier_lds();
    gemm_layer<true >(Wp + 0 * 65536, Wp + 1 * 65536, xb1, hbuf, acc, afr, lane, ln, quad, wave);
    gemm_layer<true >(Wp + 1 * 65536, Wp + 2 * 65536, xb2, hbuf, acc, afr, lane, ln, quad, wave);
    gemm_layer<false>(Wp + 2 * 65536, Wp + 3 * 65536, nullptr, hbuf, acc, afr, lane, ln, quad, wave);
    // Pack nx = acc + xb3 into fp16 (frees the fp32 accumulator for t-MLP).
#pragma unroll
    for (int i = 0; i < 4; ++i) {
        int nb = wave * 64 + 16 * i + quad * 4;
        f32x4 bv = *(const f32x4*)&xb3[nb];
#pragma unroll
        for (int j = 0; j < 4; ++j) {
            xnx[i][j][0] = (_Float16)(acc[i][j][0] + bv[0]);
            xnx[i][j][1] = (_Float16)(acc[i][j][1] + bv[1]);
            xnx[i][j][2] = (_Float16)(acc[i][j][2] + bv[2]);
            xnx[i][j][3] = (_Float16)(acc[i][j][3] + bv[3]);
        }
    }

    // ----- t-MLP -----  (afr[0] already holds tW1 g=0, prefetched above)
    layer0_scalar(x, row0, 1, tW0, tb0, hbuf, tid);
    barrier_lds();
    gemm_layer<true >(Wp + 3 * 65536, Wp + 4 * 65536, tb1, hbuf, acc, afr, lane, ln, quad, wave);
    gemm_layer<true >(Wp + 4 * 65536, Wp + 5 * 65536, tb2, hbuf, acc, afr, lane, ln, quad, wave);
    gemm_layer<false>(Wp + 5 * 65536, nullptr, nullptr, hbuf, acc, afr, lane, ln, quad, wave);

    // ----- combine: even/odd strided dot, fp32 -----
    float ev[4] = {0.f, 0.f, 0.f, 0.f};
    float od[4] = {0.f, 0.f, 0.f, 0.f};
#pragma unroll
    for (int i = 0; i < 4; ++i) {
        int nb = wave * 64 + 16 * i + quad * 4;
        f32x4 tb = *(const f32x4*)&tb3[nb];
#pragma unroll
        for (int j = 0; j < 4; ++j) {
            float a0 = (float)xnx[i][j][0], c0 = acc[i][j][0] + tb[0];
            float a1 = (float)xnx[i][j][1], c1 = acc[i][j][1] + tb[1];
            float a2 = (float)xnx[i][j][2], c2 = acc[i][j][2] + tb[2];
            float a3 = (float)xnx[i][j][3], c3 = acc[i][j][3] + tb[3];
            ev[j] += a0 * c0 + a2 * c2;      // channel parity = reg index parity
            od[j] += a1 * c1 + a3 * c3;
        }
    }
#pragma unroll
    for (int j = 0; j < 4; ++j) {            // reduce over the 4 quads
        ev[j] += __shfl_xor(ev[j], 16, 64);
        ev[j] += __shfl_xor(ev[j], 32, 64);
        od[j] += __shfl_xor(od[j], 16, 64);
        od[j] += __shfl_xor(od[j], 32, 64);
    }

    float* red = (float*)hbuf;               // hbuf dead (t-L3 read barrier passed)
    if (lane < 16) {
#pragma unroll
        for (int j = 0; j < 4; ++j) {
            red[wave * 128 + j * 32 + lane * 2 + 0] = ev[j];
            red[wave * 128 + j * 32 + lane * 2 + 1] = od[j];
        }
    }
    __syncthreads();
    if (tid < 128) {                         // sum the 4 wave partials; coalesced store
        int jj = tid >> 5, m16 = (tid >> 1) & 15, p = tid & 1;
        int base = jj * 32 + m16 * 2 + p;
        float s = red[base] + red[128 + base] + red[256 + base] + red[384 + base];
        out[(row0 + 16 * jj + m16) * 2 + p] = s;
    }
}

// ---------------------------------------------------------------------------
extern "C" void kernel_launch(void* const* d_in, const int* in_sizes, int n_in,
                              void* d_out, int out_size, void* d_ws, size_t ws_size,
                              hipStream_t stream)
{
    const float* x   = (const float*)d_in[0];
    const float* xW0 = (const float*)d_in[1];
    const float* xb0 = (const float*)d_in[2];
    const float* xW1 = (const float*)d_in[3];
    const float* xb1 = (const float*)d_in[4];
    const float* xW2 = (const float*)d_in[5];
    const float* xb2 = (const float*)d_in[6];
    const float* xW3 = (const float*)d_in[7];
    const float* xb3 = (const float*)d_in[8];
    const float* tW0 = (const float*)d_in[9];
    const float* tb0 = (const float*)d_in[10];
    const float* tW1 = (const float*)d_in[11];
    const float* tb1 = (const float*)d_in[12];
    const float* tW2 = (const float*)d_in[13];
    const float* tb2 = (const float*)d_in[14];
    const float* tW3 = (const float*)d_in[15];
    const float* tb3 = (const float*)d_in[16];

    _Float16* Wp = (_Float16*)d_ws;          // 6*65536 fp16 = 768 KB
    const int N = in_sizes[0] / 2;           // 1,000,000 (divisible by 64)

    prepack<<<1536, 256, 0, stream>>>(xW1, xW2, xW3, tW1, tW2, tW3, Wp);
    mlp_fused<<<N / 64, 256, 0, stream>>>(x, xW0, xb0, xb1, xb2, xb3,
                                          tW0, tb0, tb1, tb2, tb3,
                                          Wp, (float*)d_out);
}

// Round 5
// 1204.706 us; speedup vs baseline: 1.1287x; 1.0578x over previous
//
#include <hip/hip_runtime.h>

// SP_DNN: two fused 1->256->256->256->256 MLPs (sin activations) + strided rowwise dot.
// fp16 MFMA (16x16x32), fp32 accumulate.
//
// R5 = R4 with the register budget actually closed (R4 spilled 1.05 GB:
// demand ~164 vs (256,3) cap ~168 incl temps).
//  - afr single-buffered [4] (16 VGPR, was 32): in-nest reload right after
//    each fragment's last MFMA use (R3-proven pattern); K-loop tail reloads
//    the NEXT layer's g=0 fragments -> cross-layer L2 prefetch preserved.
//  - nx packed fp16 (+bias) in 32 VGPR; acc 64 AGPR; bfr 16; total ~148.
//  - Raw s_barrier with lgkmcnt(0)-only drain: global A loads stay in
//    flight across all activation barriers (no vmcnt(0) convoy).
//  - launch_bounds(256,3): 3 blocks/CU (12 waves/CU).

typedef _Float16 f16x8 __attribute__((ext_vector_type(8)));
typedef _Float16 f16x4 __attribute__((ext_vector_type(4)));
typedef float f32x4 __attribute__((ext_vector_type(4)));

// Swizzled hbuf byte offset: row m (0..63, 512 B stride), kbyte in [0,512).
// 16B unit index XORed with (m&7): any 8-lane chunk of a B-read covers all
// 32 banks exactly once; writeback/layer0 patterns are <=2-way (free).
__device__ __forceinline__ int hswz(int m, int kbyte) {
    return m * 512 + ((((kbyte >> 4) ^ (m & 7)) & 31) << 4) + (kbyte & 15);
}

// Raw workgroup barrier that drains LDS ops only; leaves global loads
// (vmcnt) in flight. "memory" clobber pins LDS read/write ordering.
__device__ __forceinline__ void barrier_lds() {
    asm volatile("s_waitcnt lgkmcnt(0)" ::: "memory");
    __builtin_amdgcn_s_barrier();
}

// ---------------------------------------------------------------------------
// Prepack: 6 matrices W[k][n] (256x256 f32, k-major) -> fp16 A-fragment-major:
// idx = ((((c*2+ks)*16 + nhi)*4 + quad)*16 + ln)*8 + j
//   n = nhi*16+ln, k = c*64 + ks*32 + quad*8 + j
// ---------------------------------------------------------------------------
__global__ void prepack(const float* __restrict__ xW1, const float* __restrict__ xW2,
                        const float* __restrict__ xW3, const float* __restrict__ tW1,
                        const float* __restrict__ tW2, const float* __restrict__ tW3,
                        _Float16* __restrict__ dst)
{
    int g = blockIdx.x * 256 + threadIdx.x;   // 6*65536 threads exactly
    int L = g >> 16;
    int r = g & 65535;
    int j    = r & 7;
    int ln   = (r >> 3) & 15;
    int quad = (r >> 7) & 3;
    int nhi  = (r >> 9) & 15;
    int ks   = (r >> 13) & 1;
    int c    = (r >> 14) & 3;
    const float* W;
    switch (L) {
        case 0: W = xW1; break;
        case 1: W = xW2; break;
        case 2: W = xW3; break;
        case 3: W = tW1; break;
        case 4: W = tW2; break;
        default: W = tW3; break;
    }
    int n = nhi * 16 + ln;
    int k = c * 64 + ks * 32 + quad * 8 + j;
    dst[g] = (_Float16)W[k * 256 + n];
}

// ---------------------------------------------------------------------------
// Main fused kernel. Block = 256 threads (4 waves), tile = 64 rows.
// Wave w owns out-channels [w*64, w*64+64).
// ---------------------------------------------------------------------------

__device__ __forceinline__ void layer0_scalar(
    const float* __restrict__ x, int row0, int sel,
    const float* __restrict__ W0, const float* __restrict__ b0,
    _Float16* __restrict__ hb, int tid)
{
    int m = tid >> 2;        // 64 rows, 4 threads per row
    int q = tid & 3;         // each thread does 64 of the 256 channels
    float xv = x[(row0 + m) * 2 + sel];
#pragma unroll
    for (int g = 0; g < 8; ++g) {
        int n0 = q * 64 + g * 8;
        f16x8 hv;
#pragma unroll
        for (int e = 0; e < 8; ++e) {
            float z = fmaf(xv, W0[n0 + e], b0[n0 + e]);
            hv[e] = (_Float16)__sinf(z);
        }
        *(f16x8*)((char*)hb + hswz(m, n0 * 2)) = hv;
    }
}

// One 256->256 layer over a SINGLE shared activation buffer.
// afr is caller-persistent; at entry afr holds THIS layer's g=0 fragments.
// Inside the MFMA nest, afr[i] is reloaded for g+1 right after its last use
// (single-buffer pipeline); at g=7 the reload targets Wnext's g=0 fragments,
// which stay in flight across the raw barriers (no vmcnt drain).
// D layout: col=lane&15 = batch row m, row=quad*4+r = out channel.
template<bool WRITE_H>
__device__ __forceinline__ void gemm_layer(
    const _Float16* __restrict__ Wl,     // packed layer base (65536 elems)
    const _Float16* __restrict__ Wnext,  // next layer base (nullptr at end)
    const float* __restrict__ bias,      // 256 f32 (only used if WRITE_H)
    _Float16* __restrict__ hb,           // activation buffer (read, then write)
    f32x4 acc[4][4], f16x8 afr[4],
    int lane, int ln, int quad, int wave)
{
    f32x4 zero = {0.f, 0.f, 0.f, 0.f};
#pragma unroll
    for (int i = 0; i < 4; ++i)
#pragma unroll
        for (int j = 0; j < 4; ++j)
            acc[i][j] = zero;

    // A fragment (g, i): Wl + g*8192 + wave*2048 + i*512 + lane*8
    const _Float16* abase = Wl + wave * 2048 + lane * 8;

#pragma unroll
    for (int g = 0; g < 8; ++g) {
        f16x8 bfr[4];
#pragma unroll
        for (int j = 0; j < 4; ++j) {    // B: activations, all 64 rows
            bfr[j] = *(const f16x8*)((const char*)hb +
                                     hswz(16 * j + ln, g * 64 + quad * 16));
        }
        __builtin_amdgcn_s_setprio(1);
#pragma unroll
        for (int i = 0; i < 4; ++i) {
#pragma unroll
            for (int j = 0; j < 4; ++j)
                acc[i][j] = __builtin_amdgcn_mfma_f32_16x16x32_f16(
                    afr[i], bfr[j], acc[i][j], 0, 0, 0);
            if (g < 7) {                  // reload afr[i] right after last use
                afr[i] = *(const f16x8*)(abase + (g + 1) * 8192 + i * 512);
            } else if (Wnext) {           // tail: prefetch NEXT layer's g=0
                afr[i] = *(const f16x8*)(Wnext + wave * 2048 + lane * 8 + i * 512);
            }
        }
        __builtin_amdgcn_s_setprio(0);
    }

    barrier_lds();   // all waves' B reads done; A prefetch stays in flight

    if (WRITE_H) {
#pragma unroll
        for (int i = 0; i < 4; ++i) {
            int nb = wave * 64 + 16 * i + quad * 4;          // 4 consecutive channels
            f32x4 bv = *(const f32x4*)&bias[nb];
#pragma unroll
            for (int j = 0; j < 4; ++j) {
                f16x4 hv;
                hv[0] = (_Float16)__sinf(acc[i][j][0] + bv[0]);
                hv[1] = (_Float16)__sinf(acc[i][j][1] + bv[1]);
                hv[2] = (_Float16)__sinf(acc[i][j][2] + bv[2]);
                hv[3] = (_Float16)__sinf(acc[i][j][3] + bv[3]);
                *(f16x4*)((char*)hb + hswz(16 * j + ln, nb * 2)) = hv;
            }
        }
        barrier_lds();   // writes visible before next layer's B reads
    }
}

__global__ __launch_bounds__(256, 3)
void mlp_fused(const float* __restrict__ x,
               const float* __restrict__ xW0, const float* __restrict__ xb0,
               const float* __restrict__ xb1, const float* __restrict__ xb2,
               const float* __restrict__ xb3,
               const float* __restrict__ tW0, const float* __restrict__ tb0,
               const float* __restrict__ tb1, const float* __restrict__ tb2,
               const float* __restrict__ tb3,
               const _Float16* __restrict__ Wp,
               float* __restrict__ out)
{
    __shared__ __align__(16) _Float16 hbuf[64 * 256];   // single 32 KB buffer

    const int tid = threadIdx.x;
    const int lane = tid & 63;
    const int wave = tid >> 6;       // 0..3
    const int ln = lane & 15;
    const int quad = lane >> 4;
    const int row0 = blockIdx.x * 64;

    f32x4 acc[4][4];                 // live GEMM accumulator (64 AGPR)
    f16x4 xnx[4][4];                 // x-MLP output, fp16 packed (32 regs)
    f16x8 afr[4];                    // A-fragment single buffer (16 VGPR)

    // Prefetch layer xW1 g=0 fragments; they land during layer0's sin work.
    {
        const _Float16* a0 = Wp + wave * 2048 + lane * 8;
#pragma unroll
        for (int i = 0; i < 4; ++i)
            afr[i] = *(const f16x8*)(a0 + i * 512);
    }

    // ----- x-MLP -----
    layer0_scalar(x, row0, 0, xW0, xb0, hbuf, tid);
    barrier_lds();
    gemm_layer<true >(Wp + 0 * 65536, Wp + 1 * 65536, xb1, hbuf, acc, afr, lane, ln, quad, wave);
    gemm_layer<true >(Wp + 1 * 65536, Wp + 2 * 65536, xb2, hbuf, acc, afr, lane, ln, quad, wave);
    gemm_layer<false>(Wp + 2 * 65536, Wp + 3 * 65536, nullptr, hbuf, acc, afr, lane, ln, quad, wave);
    // Pack nx = acc + xb3 into fp16 (frees the fp32 accumulator for t-MLP);
    // the tW1 g=0 A-prefetch (issued in the tail above) lands under this.
#pragma unroll
    for (int i = 0; i < 4; ++i) {
        int nb = wave * 64 + 16 * i + quad * 4;
        f32x4 bv = *(const f32x4*)&xb3[nb];
#pragma unroll
        for (int j = 0; j < 4; ++j) {
            xnx[i][j][0] = (_Float16)(acc[i][j][0] + bv[0]);
            xnx[i][j][1] = (_Float16)(acc[i][j][1] + bv[1]);
            xnx[i][j][2] = (_Float16)(acc[i][j][2] + bv[2]);
            xnx[i][j][3] = (_Float16)(acc[i][j][3] + bv[3]);
        }
    }

    // ----- t-MLP -----  (afr already holds tW1 g=0)
    layer0_scalar(x, row0, 1, tW0, tb0, hbuf, tid);
    barrier_lds();
    gemm_layer<true >(Wp + 3 * 65536, Wp + 4 * 65536, tb1, hbuf, acc, afr, lane, ln, quad, wave);
    gemm_layer<true >(Wp + 4 * 65536, Wp + 5 * 65536, tb2, hbuf, acc, afr, lane, ln, quad, wave);
    gemm_layer<false>(Wp + 5 * 65536, nullptr, nullptr, hbuf, acc, afr, lane, ln, quad, wave);

    // ----- combine: even/odd strided dot, fp32 -----
    float ev[4] = {0.f, 0.f, 0.f, 0.f};
    float od[4] = {0.f, 0.f, 0.f, 0.f};
#pragma unroll
    for (int i = 0; i < 4; ++i) {
        int nb = wave * 64 + 16 * i + quad * 4;
        f32x4 tb = *(const f32x4*)&tb3[nb];
#pragma unroll
        for (int j = 0; j < 4; ++j) {
            float a0 = (float)xnx[i][j][0], c0 = acc[i][j][0] + tb[0];
            float a1 = (float)xnx[i][j][1], c1 = acc[i][j][1] + tb[1];
            float a2 = (float)xnx[i][j][2], c2 = acc[i][j][2] + tb[2];
            float a3 = (float)xnx[i][j][3], c3 = acc[i][j][3] + tb[3];
            ev[j] += a0 * c0 + a2 * c2;      // channel parity = reg index parity
            od[j] += a1 * c1 + a3 * c3;
        }
    }
#pragma unroll
    for (int j = 0; j < 4; ++j) {            // reduce over the 4 quads
        ev[j] += __shfl_xor(ev[j], 16, 64);
        ev[j] += __shfl_xor(ev[j], 32, 64);
        od[j] += __shfl_xor(od[j], 16, 64);
        od[j] += __shfl_xor(od[j], 32, 64);
    }

    float* red = (float*)hbuf;               // hbuf dead (t-L3 read barrier passed)
    if (lane < 16) {
#pragma unroll
        for (int j = 0; j < 4; ++j) {
            red[wave * 128 + j * 32 + lane * 2 + 0] = ev[j];
            red[wave * 128 + j * 32 + lane * 2 + 1] = od[j];
        }
    }
    __syncthreads();
    if (tid < 128) {                         // sum the 4 wave partials; coalesced store
        int jj = tid >> 5, m16 = (tid >> 1) & 15, p = tid & 1;
        int base = jj * 32 + m16 * 2 + p;
        float s = red[base] + red[128 + base] + red[256 + base] + red[384 + base];
        out[(row0 + 16 * jj + m16) * 2 + p] = s;
    }
}

// ---------------------------------------------------------------------------
extern "C" void kernel_launch(void* const* d_in, const int* in_sizes, int n_in,
                              void* d_out, int out_size, void* d_ws, size_t ws_size,
                              hipStream_t stream)
{
    const float* x   = (const float*)d_in[0];
    const float* xW0 = (const float*)d_in[1];
    const float* xb0 = (const float*)d_in[2];
    const float* xW1 = (const float*)d_in[3];
    const float* xb1 = (const float*)d_in[4];
    const float* xW2 = (const float*)d_in[5];
    const float* xb2 = (const float*)d_in[6];
    const float* xW3 = (const float*)d_in[7];
    const float* xb3 = (const float*)d_in[8];
    const float* tW0 = (const float*)d_in[9];
    const float* tb0 = (const float*)d_in[10];
    const float* tW1 = (const float*)d_in[11];
    const float* tb1 = (const float*)d_in[12];
    const float* tW2 = (const float*)d_in[13];
    const float* tb2 = (const float*)d_in[14];
    const float* tW3 = (const float*)d_in[15];
    const float* tb3 = (const float*)d_in[16];

    _Float16* Wp = (_Float16*)d_ws;          // 6*65536 fp16 = 768 KB
    const int N = in_sizes[0] / 2;           // 1,000,000 (divisible by 64)

    prepack<<<1536, 256, 0, stream>>>(xW1, xW2, xW3, tW1, tW2, tW3, Wp);
    mlp_fused<<<N / 64, 256, 0, stream>>>(x, xW0, xb0, xb1, xb2, xb3,
                                          tW0, tb0, tb1, tb2, tb3,
                                          Wp, (float*)d_out);
}

// Round 6
// 1098.531 us; speedup vs baseline: 1.2378x; 1.0967x over previous
//
#include <hip/hip_runtime.h>

// SP_DNN: two fused 1->256->256->256->256 MLPs (sin activations) + strided rowwise dot.
// fp16 MFMA (16x16x32), fp32 accumulate.
//
// R6: ILP over TLP. R0-R5 evidence: serial pipe-sum (MFMA 379 + A-L2 356 +
// VALU 280 + LDS 200 us) ~= observed dur; co-resident blocks are phase-locked
// so occupancy never broke the convoy (R2), and >2 blk/CU register budgets
// never closed (R1/R4/R5 spills). New structure: x-MLP and t-MLP are
// independent -> 6 alternating GEMM phases, each GEMM's MFMA K-loop hides the
// OTHER MLP's sin-writeback in its issue-slot shadow (MFMA and VALU are
// separate pipes; ~15 free slots per 19-cyc MFMA).
//   layer0_x->x_lds, layer0_t->t_lds | x1 | t1+wbx1 | x2+wbt1 | t2+wbx2
//   | x3+wbt2 | t3 | combine
// One lgkm-only barrier per phase (7 vs 13); A-fragments prefetched cross-
// phase and stay in flight across barriers (no vmcnt drain). Both fp32
// accumulators live (128 AGPR) -> launch_bounds(256,2), 64 KB LDS, 2 blk/CU.

typedef _Float16 f16x8 __attribute__((ext_vector_type(8)));
typedef _Float16 f16x4 __attribute__((ext_vector_type(4)));
typedef float f32x4 __attribute__((ext_vector_type(4)));

// Swizzled activation-buffer byte offset: row m (0..63, 512 B stride),
// kbyte in [0,512). 16B unit index XORed with (m&7): any 8-lane chunk of a
// B-read covers all 32 banks exactly once; writeback/layer0 <=2-way (free).
__device__ __forceinline__ int hswz(int m, int kbyte) {
    return m * 512 + ((((kbyte >> 4) ^ (m & 7)) & 31) << 4) + (kbyte & 15);
}

// Raw workgroup barrier draining LDS ops only; global loads stay in flight.
__device__ __forceinline__ void barrier_lds() {
    asm volatile("s_waitcnt lgkmcnt(0)" ::: "memory");
    __builtin_amdgcn_s_barrier();
}

// ---------------------------------------------------------------------------
// Prepack: 6 matrices W[k][n] (256x256 f32, k-major) -> fp16 A-fragment-major:
// idx = ((((c*2+ks)*16 + nhi)*4 + quad)*16 + ln)*8 + j
//   n = nhi*16+ln, k = c*64 + ks*32 + quad*8 + j
// ---------------------------------------------------------------------------
__global__ void prepack(const float* __restrict__ xW1, const float* __restrict__ xW2,
                        const float* __restrict__ xW3, const float* __restrict__ tW1,
                        const float* __restrict__ tW2, const float* __restrict__ tW3,
                        _Float16* __restrict__ dst)
{
    int g = blockIdx.x * 256 + threadIdx.x;   // 6*65536 threads exactly
    int L = g >> 16;
    int r = g & 65535;
    int j    = r & 7;
    int ln   = (r >> 3) & 15;
    int quad = (r >> 7) & 3;
    int nhi  = (r >> 9) & 15;
    int ks   = (r >> 13) & 1;
    int c    = (r >> 14) & 3;
    const float* W;
    switch (L) {
        case 0: W = xW1; break;
        case 1: W = xW2; break;
        case 2: W = xW3; break;
        case 3: W = tW1; break;
        case 4: W = tW2; break;
        default: W = tW3; break;
    }
    int n = nhi * 16 + ln;
    int k = c * 64 + ks * 32 + quad * 8 + j;
    dst[g] = (_Float16)W[k * 256 + n];
}

// ---------------------------------------------------------------------------
// Main fused kernel. Block = 256 threads (4 waves), tile = 64 rows.
// Wave w owns out-channels [w*64, w*64+64) in every 256->256 layer.
// ---------------------------------------------------------------------------

__device__ __forceinline__ void layer0_scalar(
    const float* __restrict__ x, int row0, int sel,
    const float* __restrict__ W0, const float* __restrict__ b0,
    _Float16* __restrict__ hb, int tid)
{
    int m = tid >> 2;        // 64 rows, 4 threads per row
    int q = tid & 3;         // each thread does 64 of the 256 channels
    float xv = x[(row0 + m) * 2 + sel];
#pragma unroll
    for (int g = 0; g < 8; ++g) {
        int n0 = q * 64 + g * 8;
        f16x8 hv;
#pragma unroll
        for (int e = 0; e < 8; ++e) {
            float z = fmaf(xv, W0[n0 + e], b0[n0 + e]);
            hv[e] = (_Float16)__sinf(z);
        }
        *(f16x8*)((char*)hb + hswz(m, n0 * 2)) = hv;
    }
}

// One GEMM phase: acc = Wl x rb (8 K-groups, 16 MFMA each).
// If WB: the OTHER MLP's previous accumulator wacc is converted
// (sin(wacc+wbias)) and written to wb_lds, SLICED across the 8 K-group
// iterations (2 of 16 fragments per g) so the VALU work sits in the MFMA
// shadow. rb and wb_lds are different buffers -> no intra-phase barrier.
// afr holds this phase's g=0 A-fragments at entry; in-nest reload after each
// fragment's last use; g=7 reloads Wnext's g=0 (stays in flight across the
// caller's raw barrier).
template<bool WB>
__device__ __forceinline__ void gemm_phase(
    const _Float16* __restrict__ Wl,
    const _Float16* __restrict__ Wnext,    // nullptr at the end
    const _Float16* __restrict__ rb,       // LDS read buffer (activations)
    f32x4 acc[4][4],                       // built by this phase
    f32x4 wacc[4][4],                      // consumed if WB (prev phase's acc)
    const float* __restrict__ wbias,       // bias for wacc (if WB)
    _Float16* __restrict__ wb_lds,         // write buffer for sin(wacc+bias)
    f16x8 afr[4],
    int lane, int ln, int quad, int wave)
{
    f32x4 zero = {0.f, 0.f, 0.f, 0.f};
#pragma unroll
    for (int i = 0; i < 4; ++i)
#pragma unroll
        for (int j = 0; j < 4; ++j)
            acc[i][j] = zero;

    f32x4 bvv[4];
    if (WB) {
#pragma unroll
        for (int i = 0; i < 4; ++i)
            bvv[i] = *(const f32x4*)&wbias[wave * 64 + 16 * i + quad * 4];
    }

    // A fragment (g, i): Wl + g*8192 + wave*2048 + i*512 + lane*8
    const _Float16* abase = Wl + wave * 2048 + lane * 8;

#pragma unroll
    for (int g = 0; g < 8; ++g) {
        f16x8 bfr[4];
#pragma unroll
        for (int j = 0; j < 4; ++j) {    // B: activations, all 64 rows
            bfr[j] = *(const f16x8*)((const char*)rb +
                                     hswz(16 * j + ln, g * 64 + quad * 16));
        }
#pragma unroll
        for (int i = 0; i < 4; ++i) {
#pragma unroll
            for (int j = 0; j < 4; ++j)
                acc[i][j] = __builtin_amdgcn_mfma_f32_16x16x32_f16(
                    afr[i], bfr[j], acc[i][j], 0, 0, 0);
            if (g < 7) {                  // reload afr[i] right after last use
                afr[i] = *(const f16x8*)(abase + (g + 1) * 8192 + i * 512);
            } else if (Wnext) {           // tail: prefetch NEXT phase's g=0
                afr[i] = *(const f16x8*)(Wnext + wave * 2048 + lane * 8 + i * 512);
            }
        }
        if (WB) {                         // writeback slice: fragments (wi, 2 j's)
            const int wi = g >> 1;
            const int nb = wave * 64 + 16 * wi + quad * 4;
#pragma unroll
            for (int jo = 0; jo < 2; ++jo) {
                const int wj = (g & 1) * 2 + jo;
                f16x4 hv;
                hv[0] = (_Float16)__sinf(wacc[wi][wj][0] + bvv[wi][0]);
                hv[1] = (_Float16)__sinf(wacc[wi][wj][1] + bvv[wi][1]);
                hv[2] = (_Float16)__sinf(wacc[wi][wj][2] + bvv[wi][2]);
                hv[3] = (_Float16)__sinf(wacc[wi][wj][3] + bvv[wi][3]);
                *(f16x4*)((char*)wb_lds + hswz(16 * wj + ln, nb * 2)) = hv;
            }
        }
    }
}

__global__ __launch_bounds__(256, 2)
void mlp_fused(const float* __restrict__ x,
               const float* __restrict__ xW0, const float* __restrict__ xb0,
               const float* __restrict__ xb1, const float* __restrict__ xb2,
               const float* __restrict__ xb3,
               const float* __restrict__ tW0, const float* __restrict__ tb0,
               const float* __restrict__ tb1, const float* __restrict__ tb2,
               const float* __restrict__ tb3,
               const _Float16* __restrict__ Wp,
               float* __restrict__ out)
{
    __shared__ __align__(16) _Float16 hbuf[2][64 * 256];   // [0]=x acts, [1]=t acts

    const int tid = threadIdx.x;
    const int lane = tid & 63;
    const int wave = tid >> 6;       // 0..3
    const int ln = lane & 15;
    const int quad = lane >> 4;
    const int row0 = blockIdx.x * 64;

    f32x4 xacc[4][4], tacc[4][4];    // both live: 128 AGPR
    f16x8 afr[4];                    // A-fragment buffer (16 VGPR)

    // Prefetch xW1 g=0 fragments; they land during layer0's sin work.
    {
        const _Float16* a0 = Wp + wave * 2048 + lane * 8;
#pragma unroll
        for (int i = 0; i < 4; ++i)
            afr[i] = *(const f16x8*)(a0 + i * 512);
    }

    // ----- layer 0 (both MLPs) -----
    layer0_scalar(x, row0, 0, xW0, xb0, hbuf[0], tid);
    layer0_scalar(x, row0, 1, tW0, tb0, hbuf[1], tid);
    barrier_lds();

    // ----- 6 alternating GEMM phases -----
    // P1: x1
    gemm_phase<false>(Wp + 0 * 65536, Wp + 3 * 65536, hbuf[0], xacc,
                      nullptr, nullptr, nullptr, afr, lane, ln, quad, wave);
    barrier_lds();
    // P2: t1 || wb_x1 -> x_lds
    gemm_phase<true >(Wp + 3 * 65536, Wp + 1 * 65536, hbuf[1], tacc,
                      xacc, xb1, hbuf[0], afr, lane, ln, quad, wave);
    barrier_lds();
    // P3: x2 || wb_t1 -> t_lds
    gemm_phase<true >(Wp + 1 * 65536, Wp + 4 * 65536, hbuf[0], xacc,
                      tacc, tb1, hbuf[1], afr, lane, ln, quad, wave);
    barrier_lds();
    // P4: t2 || wb_x2 -> x_lds
    gemm_phase<true >(Wp + 4 * 65536, Wp + 2 * 65536, hbuf[1], tacc,
                      xacc, xb2, hbuf[0], afr, lane, ln, quad, wave);
    barrier_lds();
    // P5: x3 || wb_t2 -> t_lds
    gemm_phase<true >(Wp + 2 * 65536, Wp + 5 * 65536, hbuf[0], xacc,
                      tacc, tb2, hbuf[1], afr, lane, ln, quad, wave);
    barrier_lds();
    // P6: t3
    gemm_phase<false>(Wp + 5 * 65536, nullptr, hbuf[1], tacc,
                      nullptr, nullptr, nullptr, afr, lane, ln, quad, wave);

    // ----- combine: even/odd strided dot, fp32 -----
    float ev[4] = {0.f, 0.f, 0.f, 0.f};
    float od[4] = {0.f, 0.f, 0.f, 0.f};
#pragma unroll
    for (int i = 0; i < 4; ++i) {
        int nb = wave * 64 + 16 * i + quad * 4;
        f32x4 xb = *(const f32x4*)&xb3[nb];
        f32x4 tb = *(const f32x4*)&tb3[nb];
#pragma unroll
        for (int j = 0; j < 4; ++j) {
            float a0 = xacc[i][j][0] + xb[0], c0 = tacc[i][j][0] + tb[0];
            float a1 = xacc[i][j][1] + xb[1], c1 = tacc[i][j][1] + tb[1];
            float a2 = xacc[i][j][2] + xb[2], c2 = tacc[i][j][2] + tb[2];
            float a3 = xacc[i][j][3] + xb[3], c3 = tacc[i][j][3] + tb[3];
            ev[j] += a0 * c0 + a2 * c2;      // channel parity = reg index parity
            od[j] += a1 * c1 + a3 * c3;
        }
    }
#pragma unroll
    for (int j = 0; j < 4; ++j) {            // reduce over the 4 quads
        ev[j] += __shfl_xor(ev[j], 16, 64);
        ev[j] += __shfl_xor(ev[j], 32, 64);
        od[j] += __shfl_xor(od[j], 16, 64);
        od[j] += __shfl_xor(od[j], 32, 64);
    }

    // x_lds is dead (last read in P5, all waves passed the P5->P6 barrier).
    float* red = (float*)hbuf[0];
    if (lane < 16) {
#pragma unroll
        for (int j = 0; j < 4; ++j) {
            red[wave * 128 + j * 32 + lane * 2 + 0] = ev[j];
            red[wave * 128 + j * 32 + lane * 2 + 1] = od[j];
        }
    }
    __syncthreads();
    if (tid < 128) {                         // sum the 4 wave partials; coalesced store
        int jj = tid >> 5, m16 = (tid >> 1) & 15, p = tid & 1;
        int base = jj * 32 + m16 * 2 + p;
        float s = red[base] + red[128 + base] + red[256 + base] + red[384 + base];
        out[(row0 + 16 * jj + m16) * 2 + p] = s;
    }
}

// ---------------------------------------------------------------------------
extern "C" void kernel_launch(void* const* d_in, const int* in_sizes, int n_in,
                              void* d_out, int out_size, void* d_ws, size_t ws_size,
                              hipStream_t stream)
{
    const float* x   = (const float*)d_in[0];
    const float* xW0 = (const float*)d_in[1];
    const float* xb0 = (const float*)d_in[2];
    const float* xW1 = (const float*)d_in[3];
    const float* xb1 = (const float*)d_in[4];
    const float* xW2 = (const float*)d_in[5];
    const float* xb2 = (const float*)d_in[6];
    const float* xW3 = (const float*)d_in[7];
    const float* xb3 = (const float*)d_in[8];
    const float* tW0 = (const float*)d_in[9];
    const float* tb0 = (const float*)d_in[10];
    const float* tW1 = (const float*)d_in[11];
    const float* tb1 = (const float*)d_in[12];
    const float* tW2 = (const float*)d_in[13];
    const float* tb2 = (const float*)d_in[14];
    const float* tW3 = (const float*)d_in[15];
    const float* tb3 = (const float*)d_in[16];

    _Float16* Wp = (_Float16*)d_ws;          // 6*65536 fp16 = 768 KB
    const int N = in_sizes[0] / 2;           // 1,000,000 (divisible by 64)

    prepack<<<1536, 256, 0, stream>>>(xW1, xW2, xW3, tW1, tW2, tW3, Wp);
    mlp_fused<<<N / 64, 256, 0, stream>>>(x, xW0, xb0, xb1, xb2, xb3,
                                          tW0, tb0, tb1, tb2, tb3,
                                          Wp, (float*)d_out);
}

// Round 8
// 950.451 us; speedup vs baseline: 1.4306x; 1.1558x over previous
//
#include <hip/hip_runtime.h>

// SP_DNN: two fused 1->256->256->256->256 MLPs (sin activations) + strided rowwise dot.
// fp16 MFMA (16x16x32), fp32 accumulate.
//
// R8 = R7 (A-prefetch via global_load_lds into per-wave LDS slots) with the
// slot race closed. R7 failed (absmax 0.146): it read slot[g&1] and refilled
// the SAME slot in the same iteration; MFMAs are not memory ops, so the
// scheduler could issue the refill before the slot's ds_reads retired, and a
// congested LDS queue (>200cy backlog) let the incoming global->LDS write
// beat the pending reads. Fix (architectural, scheduler-proof):
//  - stage at the START of g, for g+1, into slot[(g+1)&1] (never the slot
//    read this iteration); at g=7 stage the NEXT layer's g0 (-> slot0).
//  - 's_waitcnt lgkmcnt(0)' inline-asm immediately before every stage issue:
//    in-order wave issue => all prior ds_reads (incl. last iter's reads of
//    the target slot) are RETIRED before the overwrite can issue.
//  - vmcnt invariant: stage(+4) -> vmcnt(4) retires this g's 4 loads (the
//    oldest stage ops; any older flat ops only drain earlier). vmcnt(0) only
//    at the very last g of the last layer.
// Rest as R7: params (xW0/xb0/tW0/tb0 + 6 biases) preloaded to LDS; single
// 32 KB act buffer (read -> bar -> writeback -> bar); lgkm-only barriers so
// stage loads stay in flight across phases. LDS 74 KB -> 2 blocks/CU.

typedef _Float16 f16x8 __attribute__((ext_vector_type(8)));
typedef _Float16 f16x4 __attribute__((ext_vector_type(4)));
typedef float f32x4 __attribute__((ext_vector_type(4)));

// Swizzled act-buffer byte offset: row m (0..63, 512 B stride), kbyte in
// [0,512). 16B unit index XORed with (m&7): any 8-lane chunk of a B-read
// covers all 32 banks exactly once; writeback/layer0 <=2-way (free).
__device__ __forceinline__ int hswz(int m, int kbyte) {
    return m * 512 + ((((kbyte >> 4) ^ (m & 7)) & 31) << 4) + (kbyte & 15);
}

// Raw workgroup barrier draining LDS ops only; global loads stay in flight.
__device__ __forceinline__ void barrier_lds() {
    asm volatile("s_waitcnt lgkmcnt(0)" ::: "memory");
    __builtin_amdgcn_s_barrier();
}

// Async global->LDS, 16 B per lane: lane l reads 16B at (g + l*16B) and HW
// writes it to (wave-uniform lds base) + l*16B.
__device__ __forceinline__ void stage_frag(const _Float16* g, _Float16* l) {
    __builtin_amdgcn_global_load_lds(
        (const __attribute__((address_space(1))) unsigned int*)g,
        (__attribute__((address_space(3))) unsigned int*)l,
        16, 0, 0);
}

// ---------------------------------------------------------------------------
// Prepack: 6 matrices W[k][n] (256x256 f32, k-major) -> fp16 A-fragment-major:
// idx = ((((c*2+ks)*16 + nhi)*4 + quad)*16 + ln)*8 + j
//   n = nhi*16+ln, k = c*64 + ks*32 + quad*8 + j
// ---------------------------------------------------------------------------
__global__ void prepack(const float* __restrict__ xW1, const float* __restrict__ xW2,
                        const float* __restrict__ xW3, const float* __restrict__ tW1,
                        const float* __restrict__ tW2, const float* __restrict__ tW3,
                        _Float16* __restrict__ dst)
{
    int g = blockIdx.x * 256 + threadIdx.x;   // 6*65536 threads exactly
    int L = g >> 16;
    int r = g & 65535;
    int j    = r & 7;
    int ln   = (r >> 3) & 15;
    int quad = (r >> 7) & 3;
    int nhi  = (r >> 9) & 15;
    int ks   = (r >> 13) & 1;
    int c    = (r >> 14) & 3;
    const float* W;
    switch (L) {
        case 0: W = xW1; break;
        case 1: W = xW2; break;
        case 2: W = xW3; break;
        case 3: W = tW1; break;
        case 4: W = tW2; break;
        default: W = tW3; break;
    }
    int n = nhi * 16 + ln;
    int k = c * 64 + ks * 32 + quad * 8 + j;
    dst[g] = (_Float16)W[k * 256 + n];
}

// ---------------------------------------------------------------------------
// Main fused kernel. Block = 256 threads (4 waves), tile = 64 rows.
// Wave w owns out-channels [w*64, w*64+64).
// ---------------------------------------------------------------------------

__device__ __forceinline__ void layer0_scalar(
    float xv, const float* __restrict__ W0, const float* __restrict__ b0,
    _Float16* __restrict__ hb, int tid)
{
    int m = tid >> 2;        // 64 rows, 4 threads per row
    int q = tid & 3;         // each thread does 64 of the 256 channels
#pragma unroll
    for (int g = 0; g < 8; ++g) {
        int n0 = q * 64 + g * 8;
        f16x8 hv;
#pragma unroll
        for (int e = 0; e < 8; ++e) {
            float z = fmaf(xv, W0[n0 + e], b0[n0 + e]);
            hv[e] = (_Float16)__sinf(z);
        }
        *(f16x8*)((char*)hb + hswz(m, n0 * 2)) = hv;
    }
}

// One 256->256 layer. Per g:
//   [lgkmcnt(0); stage g+1 -> slot[(g+1)&1]]   (g=7 stages Wnext g0 -> slot0)
//   [vmcnt(4): this g's 4 loads (oldest) landed]
//   [ds_read afr from slot[g&1]; ds_read bfr from hb; 16 MFMA]
// At entry slot0 holds this layer's g0 (4 loads in flight or landed).
template<bool WRITE_H, bool HAS_NEXT>
__device__ __forceinline__ void gemm_layer(
    const _Float16* __restrict__ Wl,     // this layer's packed base
    const _Float16* __restrict__ Wnext,  // next layer's packed base (if HAS_NEXT)
    const float* __restrict__ bias,      // LDS-resident bias (if WRITE_H)
    _Float16* __restrict__ hb,           // activation buffer (read, then write)
    _Float16* __restrict__ stg,          // this wave's stage base (2 x 2048 halfs)
    f32x4 acc[4][4],
    int lane, int ln, int quad, int wave)
{
    f32x4 zero = {0.f, 0.f, 0.f, 0.f};
#pragma unroll
    for (int i = 0; i < 4; ++i)
#pragma unroll
        for (int j = 0; j < 4; ++j)
            acc[i][j] = zero;

#pragma unroll
    for (int g = 0; g < 8; ++g) {
        // ---- stage A for g+1 into the OTHER slot (race-free by construction:
        // the lgkmcnt(0) retires every prior ds_read -- including last
        // iteration's reads of the target slot -- before this issues).
        if (g < 7 || HAS_NEXT) {
            asm volatile("s_waitcnt lgkmcnt(0)" ::: "memory");
            _Float16* dst = stg + ((g + 1) & 1) * 2048;
            const _Float16* src = (g < 7)
                ? Wl + (g + 1) * 8192 + wave * 2048 + lane * 8
                : Wnext + wave * 2048 + lane * 8;
#pragma unroll
            for (int i = 0; i < 4; ++i)
                stage_frag(src + i * 512, dst + i * 512);
        }

        // ---- wait for THIS g's A-data (staged one iteration ago).
        if (g == 7 && !HAS_NEXT)
            asm volatile("s_waitcnt vmcnt(0)" ::: "memory");
        else
            asm volatile("s_waitcnt vmcnt(4)" ::: "memory");

        f16x8 afr[4];
#pragma unroll
        for (int i = 0; i < 4; ++i)
            afr[i] = *(const f16x8*)(stg + (g & 1) * 2048 + i * 512 + lane * 8);

        f16x8 bfr[4];
#pragma unroll
        for (int j = 0; j < 4; ++j)      // B: activations, all 64 rows
            bfr[j] = *(const f16x8*)((const char*)hb +
                                     hswz(16 * j + ln, g * 64 + quad * 16));

        __builtin_amdgcn_s_setprio(1);
#pragma unroll
        for (int i = 0; i < 4; ++i)
#pragma unroll
            for (int j = 0; j < 4; ++j)
                acc[i][j] = __builtin_amdgcn_mfma_f32_16x16x32_f16(
                    afr[i], bfr[j], acc[i][j], 0, 0, 0);
        __builtin_amdgcn_s_setprio(0);
    }

    barrier_lds();   // all waves' B reads done; stage loads stay in flight

    if (WRITE_H) {
#pragma unroll
        for (int i = 0; i < 4; ++i) {
            int nb = wave * 64 + 16 * i + quad * 4;          // 4 consecutive channels
            f32x4 bv = *(const f32x4*)&bias[nb];             // LDS read
#pragma unroll
            for (int j = 0; j < 4; ++j) {
                f16x4 hv;
                hv[0] = (_Float16)__sinf(acc[i][j][0] + bv[0]);
                hv[1] = (_Float16)__sinf(acc[i][j][1] + bv[1]);
                hv[2] = (_Float16)__sinf(acc[i][j][2] + bv[2]);
                hv[3] = (_Float16)__sinf(acc[i][j][3] + bv[3]);
                *(f16x4*)((char*)hb + hswz(16 * j + ln, nb * 2)) = hv;
            }
        }
        barrier_lds();   // writes visible before next layer's B reads
    }
}

__global__ __launch_bounds__(256, 2)
void mlp_fused(const float* __restrict__ x,
               const float* __restrict__ xW0, const float* __restrict__ xb0,
               const float* __restrict__ xb1, const float* __restrict__ xb2,
               const float* __restrict__ xb3,
               const float* __restrict__ tW0, const float* __restrict__ tb0,
               const float* __restrict__ tb1, const float* __restrict__ tb2,
               const float* __restrict__ tb3,
               const _Float16* __restrict__ Wp,
               float* __restrict__ out)
{
    __shared__ __align__(16) _Float16 hbuf[64 * 256];      // 32 KB activations
    __shared__ __align__(16) _Float16 stage[4][2][2048];   // 32 KB A-stage (per wave)
    __shared__ __align__(16) float    params[10 * 256];    // 10 KB small params

    const int tid = threadIdx.x;
    const int lane = tid & 63;
    const int wave = tid >> 6;       // 0..3
    const int ln = lane & 15;
    const int quad = lane >> 4;
    const int row0 = blockIdx.x * 64;

    // Preload all small params to LDS.
    // segs: 0 xW0, 1 xb0, 2 tW0, 3 tb0, 4 xb1, 5 xb2, 6 xb3, 7 tb1, 8 tb2, 9 tb3
    {
        const float* psrc[10] = {xW0, xb0, tW0, tb0, xb1, xb2, xb3, tb1, tb2, tb3};
#pragma unroll
        for (int s = 0; s < 10; ++s)
            params[s * 256 + tid] = psrc[s][tid];
    }
    const float2 xv2 = ((const float2*)x)[row0 + (tid >> 2)];  // both MLP inputs
    barrier_lds();                    // params visible to all waves

    _Float16* stg = &stage[wave][0][0];
    f32x4 xacc[4][4], tacc[4][4];     // 128 AGPR

    // Stage prologue: xW1 g0 -> slot0 (4 loads in flight).
#pragma unroll
    for (int i = 0; i < 4; ++i)
        stage_frag(Wp + wave * 2048 + lane * 8 + i * 512, stg + i * 512);

    // ----- x-MLP -----
    layer0_scalar(xv2.x, &params[0], &params[256], hbuf, tid);
    barrier_lds();                    // hbuf (layer0 acts) visible

    gemm_layer<true , true >(Wp + 0 * 65536, Wp + 1 * 65536, &params[4 * 256],
                             hbuf, stg, xacc, lane, ln, quad, wave);
    gemm_layer<true , true >(Wp + 1 * 65536, Wp + 2 * 65536, &params[5 * 256],
                             hbuf, stg, xacc, lane, ln, quad, wave);
    gemm_layer<false, true >(Wp + 2 * 65536, Wp + 3 * 65536, nullptr,
                             hbuf, stg, xacc, lane, ln, quad, wave);
    // xacc = x-MLP layer3 pre-bias output. tW1 g0 already staged (slot0).

    // ----- t-MLP -----
    layer0_scalar(xv2.y, &params[2 * 256], &params[3 * 256], hbuf, tid);
    barrier_lds();

    gemm_layer<true , true >(Wp + 3 * 65536, Wp + 4 * 65536, &params[7 * 256],
                             hbuf, stg, tacc, lane, ln, quad, wave);
    gemm_layer<true , true >(Wp + 4 * 65536, Wp + 5 * 65536, &params[8 * 256],
                             hbuf, stg, tacc, lane, ln, quad, wave);
    gemm_layer<false, false>(Wp + 5 * 65536, nullptr, nullptr,
                             hbuf, stg, tacc, lane, ln, quad, wave);

    // ----- combine: even/odd strided dot, fp32 -----
    const float* xb3l = &params[6 * 256];
    const float* tb3l = &params[9 * 256];
    float ev[4] = {0.f, 0.f, 0.f, 0.f};
    float od[4] = {0.f, 0.f, 0.f, 0.f};
#pragma unroll
    for (int i = 0; i < 4; ++i) {
        int nb = wave * 64 + 16 * i + quad * 4;
        f32x4 xb = *(const f32x4*)&xb3l[nb];
        f32x4 tb = *(const f32x4*)&tb3l[nb];
#pragma unroll
        for (int j = 0; j < 4; ++j) {
            float a0 = xacc[i][j][0] + xb[0], c0 = tacc[i][j][0] + tb[0];
            float a1 = xacc[i][j][1] + xb[1], c1 = tacc[i][j][1] + tb[1];
            float a2 = xacc[i][j][2] + xb[2], c2 = tacc[i][j][2] + tb[2];
            float a3 = xacc[i][j][3] + xb[3], c3 = tacc[i][j][3] + tb[3];
            ev[j] += a0 * c0 + a2 * c2;      // channel parity = reg index parity
            od[j] += a1 * c1 + a3 * c3;
        }
    }
#pragma unroll
    for (int j = 0; j < 4; ++j) {            // reduce over the 4 quads
        ev[j] += __shfl_xor(ev[j], 16, 64);
        ev[j] += __shfl_xor(ev[j], 32, 64);
        od[j] += __shfl_xor(od[j], 16, 64);
        od[j] += __shfl_xor(od[j], 32, 64);
    }

    float* red = (float*)hbuf;               // hbuf dead (t-L3 read barrier passed)
    if (lane < 16) {
#pragma unroll
        for (int j = 0; j < 4; ++j) {
            red[wave * 128 + j * 32 + lane * 2 + 0] = ev[j];
            red[wave * 128 + j * 32 + lane * 2 + 1] = od[j];
        }
    }
    __syncthreads();
    if (tid < 128) {                         // sum the 4 wave partials; coalesced store
        int jj = tid >> 5, m16 = (tid >> 1) & 15, p = tid & 1;
        int base = jj * 32 + m16 * 2 + p;
        float s = red[base] + red[128 + base] + red[256 + base] + red[384 + base];
        out[(row0 + 16 * jj + m16) * 2 + p] = s;
    }
}

// ---------------------------------------------------------------------------
extern "C" void kernel_launch(void* const* d_in, const int* in_sizes, int n_in,
                              void* d_out, int out_size, void* d_ws, size_t ws_size,
                              hipStream_t stream)
{
    const float* x   = (const float*)d_in[0];
    const float* xW0 = (const float*)d_in[1];
    const float* xb0 = (const float*)d_in[2];
    const float* xW1 = (const float*)d_in[3];
    const float* xb1 = (const float*)d_in[4];
    const float* xW2 = (const float*)d_in[5];
    const float* xb2 = (const float*)d_in[6];
    const float* xW3 = (const float*)d_in[7];
    const float* xb3 = (const float*)d_in[8];
    const float* tW0 = (const float*)d_in[9];
    const float* tb0 = (const float*)d_in[10];
    const float* tW1 = (const float*)d_in[11];
    const float* tb1 = (const float*)d_in[12];
    const float* tW2 = (const float*)d_in[13];
    const float* tb2 = (const float*)d_in[14];
    const float* tW3 = (const float*)d_in[15];
    const float* tb3 = (const float*)d_in[16];

    _Float16* Wp = (_Float16*)d_ws;          // 6*65536 fp16 = 768 KB
    const int N = in_sizes[0] / 2;           // 1,000,000 (divisible by 64)

    prepack<<<1536, 256, 0, stream>>>(xW1, xW2, xW3, tW1, tW2, tW3, Wp);
    mlp_fused<<<N / 64, 256, 0, stream>>>(x, xW0, xb0, xb1, xb2, xb3,
                                          tW0, tb0, tb1, tb2, tb3,
                                          Wp, (float*)d_out);
}

// Round 9
// 870.355 us; speedup vs baseline: 1.5623x; 1.0920x over previous
//
#include <hip/hip_runtime.h>

// SP_DNN: two fused 1->256->256->256->256 MLPs (sin activations) + strided rowwise dot.
// fp16 MFMA (16x16x32), fp32 accumulate.
//
// R9: depth-2 A-prefetch IN REGISTERS (R8's win minus its LDS cost).
// R8 (LDS staging, 950us) proved prefetch depth 2 is the lever, but its
// stage system was 256 KB/layer/block of LDS traffic (~560us of LDS-pipe
// per CU incl. B-reads) and +4.8e7 bank conflicts. R9 keeps the depth with
// afr[2][4] VGPR double-buffer: at iter g the MFMAs consume buf[g&1], then
// 4 global_load_dwordx4 refill that same buffer for g+2 (WAR-safe
// reload-after-last-use, correctness-proven in R6); at g=6/7 the refill
// targets the NEXT layer's g0/g1 -> cross-layer pipeline, no drain.
// Compiler's per-register scoreboard supplies precise vmcnt waits; raw
// lgkm-only barriers keep loads in flight across phases.
// LDS/layer: 400 -> 144 KB (B-reads 128 + writeback 16); block LDS 42 KB.
// Regs: 128 AGPR (xacc+tacc) + ~120 VGPR (afr 32, bfr 16, addr) <= 256.

typedef _Float16 f16x8 __attribute__((ext_vector_type(8)));
typedef _Float16 f16x4 __attribute__((ext_vector_type(4)));
typedef float f32x4 __attribute__((ext_vector_type(4)));

// Swizzled act-buffer byte offset: row m (0..63, 512 B stride), kbyte in
// [0,512). 16B unit index XORed with (m&7): any 8-lane chunk of a B-read
// covers all 32 banks exactly once; writeback/layer0 <=2-way (free).
__device__ __forceinline__ int hswz(int m, int kbyte) {
    return m * 512 + ((((kbyte >> 4) ^ (m & 7)) & 31) << 4) + (kbyte & 15);
}

// Raw workgroup barrier draining LDS ops only; global loads stay in flight.
__device__ __forceinline__ void barrier_lds() {
    asm volatile("s_waitcnt lgkmcnt(0)" ::: "memory");
    __builtin_amdgcn_s_barrier();
}

// ---------------------------------------------------------------------------
// Prepack: 6 matrices W[k][n] (256x256 f32, k-major) -> fp16 A-fragment-major:
// idx = ((((c*2+ks)*16 + nhi)*4 + quad)*16 + ln)*8 + j
//   n = nhi*16+ln, k = c*64 + ks*32 + quad*8 + j
// ---------------------------------------------------------------------------
__global__ void prepack(const float* __restrict__ xW1, const float* __restrict__ xW2,
                        const float* __restrict__ xW3, const float* __restrict__ tW1,
                        const float* __restrict__ tW2, const float* __restrict__ tW3,
                        _Float16* __restrict__ dst)
{
    int g = blockIdx.x * 256 + threadIdx.x;   // 6*65536 threads exactly
    int L = g >> 16;
    int r = g & 65535;
    int j    = r & 7;
    int ln   = (r >> 3) & 15;
    int quad = (r >> 7) & 3;
    int nhi  = (r >> 9) & 15;
    int ks   = (r >> 13) & 1;
    int c    = (r >> 14) & 3;
    const float* W;
    switch (L) {
        case 0: W = xW1; break;
        case 1: W = xW2; break;
        case 2: W = xW3; break;
        case 3: W = tW1; break;
        case 4: W = tW2; break;
        default: W = tW3; break;
    }
    int n = nhi * 16 + ln;
    int k = c * 64 + ks * 32 + quad * 8 + j;
    dst[g] = (_Float16)W[k * 256 + n];
}

// ---------------------------------------------------------------------------
// Main fused kernel. Block = 256 threads (4 waves), tile = 64 rows.
// Wave w owns out-channels [w*64, w*64+64).
// ---------------------------------------------------------------------------

__device__ __forceinline__ void layer0_scalar(
    float xv, const float* __restrict__ W0, const float* __restrict__ b0,
    _Float16* __restrict__ hb, int tid)
{
    int m = tid >> 2;        // 64 rows, 4 threads per row
    int q = tid & 3;         // each thread does 64 of the 256 channels
#pragma unroll
    for (int g = 0; g < 8; ++g) {
        int n0 = q * 64 + g * 8;
        f16x8 hv;
#pragma unroll
        for (int e = 0; e < 8; ++e) {
            float z = fmaf(xv, W0[n0 + e], b0[n0 + e]);
            hv[e] = (_Float16)__sinf(z);
        }
        *(f16x8*)((char*)hb + hswz(m, n0 * 2)) = hv;
    }
}

// One 256->256 layer. A-fragments live in the caller-persistent afr[2][4]
// register double-buffer: at entry buf0 = this layer's g0, buf1 = g1 (loads
// possibly still in flight; the compiler's scoreboard waits before first
// MFMA use). Per g: ds_read bfr, 16 MFMA on buf[g&1], then refill buf[g&1]
// with g+2 (g=6/7: the NEXT layer's g0/g1) -- reload strictly after the
// consuming MFMAs in program order (WAR-safe, R6-proven).
template<bool WRITE_H, bool HAS_NEXT>
__device__ __forceinline__ void gemm_layer(
    const _Float16* __restrict__ Wl,     // this layer's packed base
    const _Float16* __restrict__ Wnext,  // next layer's packed base (if HAS_NEXT)
    const float* __restrict__ bias,      // LDS-resident bias (if WRITE_H)
    _Float16* __restrict__ hb,           // activation buffer (read, then write)
    f32x4 acc[4][4], f16x8 afr[2][4],
    int lane, int ln, int quad, int wave)
{
    f32x4 zero = {0.f, 0.f, 0.f, 0.f};
#pragma unroll
    for (int i = 0; i < 4; ++i)
#pragma unroll
        for (int j = 0; j < 4; ++j)
            acc[i][j] = zero;

    // A fragment (g, i): Wl + g*8192 + wave*2048 + i*512 + lane*8
    const _Float16* abase = Wl + wave * 2048 + lane * 8;

#pragma unroll
    for (int g = 0; g < 8; ++g) {
        f16x8 bfr[4];
#pragma unroll
        for (int j = 0; j < 4; ++j)      // B: activations, all 64 rows
            bfr[j] = *(const f16x8*)((const char*)hb +
                                     hswz(16 * j + ln, g * 64 + quad * 16));

        __builtin_amdgcn_s_setprio(1);
#pragma unroll
        for (int i = 0; i < 4; ++i)
#pragma unroll
            for (int j = 0; j < 4; ++j)
                acc[i][j] = __builtin_amdgcn_mfma_f32_16x16x32_f16(
                    afr[g & 1][i], bfr[j], acc[i][j], 0, 0, 0);
        __builtin_amdgcn_s_setprio(0);

        // Refill buf[g&1] for g+2 (program-order after its last MFMA use).
        if (g < 6) {
#pragma unroll
            for (int i = 0; i < 4; ++i)
                afr[g & 1][i] = *(const f16x8*)(abase + (g + 2) * 8192 + i * 512);
        } else if (HAS_NEXT) {           // g=6 -> next g0 (buf0); g=7 -> next g1 (buf1)
#pragma unroll
            for (int i = 0; i < 4; ++i)
                afr[g & 1][i] = *(const f16x8*)(Wnext + (g - 6) * 8192 +
                                                wave * 2048 + lane * 8 + i * 512);
        }
    }

    barrier_lds();   // all waves' B reads done; A loads stay in flight

    if (WRITE_H) {
#pragma unroll
        for (int i = 0; i < 4; ++i) {
            int nb = wave * 64 + 16 * i + quad * 4;          // 4 consecutive channels
            f32x4 bv = *(const f32x4*)&bias[nb];             // LDS read
#pragma unroll
            for (int j = 0; j < 4; ++j) {
                f16x4 hv;
                hv[0] = (_Float16)__sinf(acc[i][j][0] + bv[0]);
                hv[1] = (_Float16)__sinf(acc[i][j][1] + bv[1]);
                hv[2] = (_Float16)__sinf(acc[i][j][2] + bv[2]);
                hv[3] = (_Float16)__sinf(acc[i][j][3] + bv[3]);
                *(f16x4*)((char*)hb + hswz(16 * j + ln, nb * 2)) = hv;
            }
        }
        barrier_lds();   // writes visible before next layer's B reads
    }
}

__global__ __launch_bounds__(256, 2)
void mlp_fused(const float* __restrict__ x,
               const float* __restrict__ xW0, const float* __restrict__ xb0,
               const float* __restrict__ xb1, const float* __restrict__ xb2,
               const float* __restrict__ xb3,
               const float* __restrict__ tW0, const float* __restrict__ tb0,
               const float* __restrict__ tb1, const float* __restrict__ tb2,
               const float* __restrict__ tb3,
               const _Float16* __restrict__ Wp,
               float* __restrict__ out)
{
    __shared__ __align__(16) _Float16 hbuf[64 * 256];      // 32 KB activations
    __shared__ __align__(16) float    params[10 * 256];    // 10 KB small params

    const int tid = threadIdx.x;
    const int lane = tid & 63;
    const int wave = tid >> 6;       // 0..3
    const int ln = lane & 15;
    const int quad = lane >> 4;
    const int row0 = blockIdx.x * 64;

    // Preload all small params to LDS.
    // segs: 0 xW0, 1 xb0, 2 tW0, 3 tb0, 4 xb1, 5 xb2, 6 xb3, 7 tb1, 8 tb2, 9 tb3
    {
        const float* psrc[10] = {xW0, xb0, tW0, tb0, xb1, xb2, xb3, tb1, tb2, tb3};
#pragma unroll
        for (int s = 0; s < 10; ++s)
            params[s * 256 + tid] = psrc[s][tid];
    }
    const float2 xv2 = ((const float2*)x)[row0 + (tid >> 2)];  // both MLP inputs

    f32x4 xacc[4][4], tacc[4][4];    // 128 AGPR
    f16x8 afr[2][4];                 // A-fragment register double-buffer (32 VGPR)

    // Prologue: xW1 g0 -> buf0, g1 -> buf1; they land during layer0's sin work.
#pragma unroll
    for (int s = 0; s < 2; ++s)
#pragma unroll
        for (int i = 0; i < 4; ++i)
            afr[s][i] = *(const f16x8*)(Wp + s * 8192 + wave * 2048 +
                                        lane * 8 + i * 512);
    barrier_lds();                    // params visible to all waves

    // ----- x-MLP -----
    layer0_scalar(xv2.x, &params[0], &params[256], hbuf, tid);
    barrier_lds();                    // hbuf (layer0 acts) visible

    gemm_layer<true , true >(Wp + 0 * 65536, Wp + 1 * 65536, &params[4 * 256],
                             hbuf, xacc, afr, lane, ln, quad, wave);
    gemm_layer<true , true >(Wp + 1 * 65536, Wp + 2 * 65536, &params[5 * 256],
                             hbuf, xacc, afr, lane, ln, quad, wave);
    gemm_layer<false, true >(Wp + 2 * 65536, Wp + 3 * 65536, nullptr,
                             hbuf, xacc, afr, lane, ln, quad, wave);
    // xacc = x-MLP layer3 pre-bias output. tW1 g0/g1 already loading (afr).

    // ----- t-MLP -----
    layer0_scalar(xv2.y, &params[2 * 256], &params[3 * 256], hbuf, tid);
    barrier_lds();

    gemm_layer<true , true >(Wp + 3 * 65536, Wp + 4 * 65536, &params[7 * 256],
                             hbuf, tacc, afr, lane, ln, quad, wave);
    gemm_layer<true , true >(Wp + 4 * 65536, Wp + 5 * 65536, &params[8 * 256],
                             hbuf, tacc, afr, lane, ln, quad, wave);
    gemm_layer<false, false>(Wp + 5 * 65536, nullptr, nullptr,
                             hbuf, tacc, afr, lane, ln, quad, wave);

    // ----- combine: even/odd strided dot, fp32 -----
    const float* xb3l = &params[6 * 256];
    const float* tb3l = &params[9 * 256];
    float ev[4] = {0.f, 0.f, 0.f, 0.f};
    float od[4] = {0.f, 0.f, 0.f, 0.f};
#pragma unroll
    for (int i = 0; i < 4; ++i) {
        int nb = wave * 64 + 16 * i + quad * 4;
        f32x4 xb = *(const f32x4*)&xb3l[nb];
        f32x4 tb = *(const f32x4*)&tb3l[nb];
#pragma unroll
        for (int j = 0; j < 4; ++j) {
            float a0 = xacc[i][j][0] + xb[0], c0 = tacc[i][j][0] + tb[0];
            float a1 = xacc[i][j][1] + xb[1], c1 = tacc[i][j][1] + tb[1];
            float a2 = xacc[i][j][2] + xb[2], c2 = tacc[i][j][2] + tb[2];
            float a3 = xacc[i][j][3] + xb[3], c3 = tacc[i][j][3] + tb[3];
            ev[j] += a0 * c0 + a2 * c2;      // channel parity = reg index parity
            od[j] += a1 * c1 + a3 * c3;
        }
    }
#pragma unroll
    for (int j = 0; j < 4; ++j) {            // reduce over the 4 quads
        ev[j] += __shfl_xor(ev[j], 16, 64);
        ev[j] += __shfl_xor(ev[j], 32, 64);
        od[j] += __shfl_xor(od[j], 16, 64);
        od[j] += __shfl_xor(od[j], 32, 64);
    }

    float* red = (float*)hbuf;               // hbuf dead (t-L3 read barrier passed)
    if (lane < 16) {
#pragma unroll
        for (int j = 0; j < 4; ++j) {
            red[wave * 128 + j * 32 + lane * 2 + 0] = ev[j];
            red[wave * 128 + j * 32 + lane * 2 + 1] = od[j];
        }
    }
    __syncthreads();
    if (tid < 128) {                         // sum the 4 wave partials; coalesced store
        int jj = tid >> 5, m16 = (tid >> 1) & 15, p = tid & 1;
        int base = jj * 32 + m16 * 2 + p;
        float s = red[base] + red[128 + base] + red[256 + base] + red[384 + base];
        out[(row0 + 16 * jj + m16) * 2 + p] = s;
    }
}

// ---------------------------------------------------------------------------
extern "C" void kernel_launch(void* const* d_in, const int* in_sizes, int n_in,
                              void* d_out, int out_size, void* d_ws, size_t ws_size,
                              hipStream_t stream)
{
    const float* x   = (const float*)d_in[0];
    const float* xW0 = (const float*)d_in[1];
    const float* xb0 = (const float*)d_in[2];
    const float* xW1 = (const float*)d_in[3];
    const float* xb1 = (const float*)d_in[4];
    const float* xW2 = (const float*)d_in[5];
    const float* xb2 = (const float*)d_in[6];
    const float* xW3 = (const float*)d_in[7];
    const float* xb3 = (const float*)d_in[8];
    const float* tW0 = (const float*)d_in[9];
    const float* tb0 = (const float*)d_in[10];
    const float* tW1 = (const float*)d_in[11];
    const float* tb1 = (const float*)d_in[12];
    const float* tW2 = (const float*)d_in[13];
    const float* tb2 = (const float*)d_in[14];
    const float* tW3 = (const float*)d_in[15];
    const float* tb3 = (const float*)d_in[16];

    _Float16* Wp = (_Float16*)d_ws;          // 6*65536 fp16 = 768 KB
    const int N = in_sizes[0] / 2;           // 1,000,000 (divisible by 64)

    prepack<<<1536, 256, 0, stream>>>(xW1, xW2, xW3, tW1, tW2, tW3, Wp);
    mlp_fused<<<N / 64, 256, 0, stream>>>(x, xW0, xb0, xb1, xb2, xb3,
                                          tW0, tb0, tb1, tb2, tb3,
                                          Wp, (float*)d_out);
}

// Round 10
// 855.228 us; speedup vs baseline: 1.5899x; 1.0177x over previous
//
#include <hip/hip_runtime.h>

// SP_DNN: two fused 1->256->256->256->256 MLPs (sin activations) + strided rowwise dot.
// fp16 MFMA (16x16x32), fp32 accumulate.
//
// R10 = R9 (depth-2 register A-prefetch, 870us, MfmaUtil 44%) + R6's x/t
// phase-interleave (which was neutral pre-R9 because the K-loop was then
// A-latency-starved and had no MFMA shadow to hide work in):
//  - 6 alternating GEMM phases: x1 | t1+wbx1 | x2+wbt1 | t2+wbx2 | x3+wbt2
//    | t3. The OTHER MLP's sin+writeback is sliced across the 8 K-groups
//    (2 of 16 fragments per g) -> its VALU+LDS-write sits in the MFMA
//    issue-slot shadow instead of a serial between-barrier phase.
//  - layer0_t sliced into P1's K-loop the same way (1 group per g).
//  - One lgkm-only barrier per phase (8 vs 13); afr[2][4] depth-2 refill
//    chains across phases (g=6/7 load the NEXT phase's g0/g1).
//  - layer0 split n0 = g*32+q*8 (was q*64+g*8): the 4 per-wave q-addresses
//    land in 4 distinct LDS banks (stride-256B same-bank fix, ~0.5e8 confl).
//  - wb bias read per-slice from LDS params (no bvv[4] register cache):
//    keeps ArchVGPR ~R9 level; 128 AGPR + ~125 VGPR <= 256 cap at 2 blk/CU.

typedef _Float16 f16x8 __attribute__((ext_vector_type(8)));
typedef _Float16 f16x4 __attribute__((ext_vector_type(4)));
typedef float f32x4 __attribute__((ext_vector_type(4)));

// Swizzled act-buffer byte offset: row m (0..63, 512 B stride), kbyte in
// [0,512). 16B unit index XORed with (m&7): any 8-lane chunk of a B-read
// covers all 32 banks exactly once; writeback/layer0 <=2-way (free).
__device__ __forceinline__ int hswz(int m, int kbyte) {
    return m * 512 + ((((kbyte >> 4) ^ (m & 7)) & 31) << 4) + (kbyte & 15);
}

// Raw workgroup barrier draining LDS ops only; global loads stay in flight.
__device__ __forceinline__ void barrier_lds() {
    asm volatile("s_waitcnt lgkmcnt(0)" ::: "memory");
    __builtin_amdgcn_s_barrier();
}

// ---------------------------------------------------------------------------
// Prepack: 6 matrices W[k][n] (256x256 f32, k-major) -> fp16 A-fragment-major:
// idx = ((((c*2+ks)*16 + nhi)*4 + quad)*16 + ln)*8 + j
//   n = nhi*16+ln, k = c*64 + ks*32 + quad*8 + j
// ---------------------------------------------------------------------------
__global__ void prepack(const float* __restrict__ xW1, const float* __restrict__ xW2,
                        const float* __restrict__ xW3, const float* __restrict__ tW1,
                        const float* __restrict__ tW2, const float* __restrict__ tW3,
                        _Float16* __restrict__ dst)
{
    int g = blockIdx.x * 256 + threadIdx.x;   // 6*65536 threads exactly
    int L = g >> 16;
    int r = g & 65535;
    int j    = r & 7;
    int ln   = (r >> 3) & 15;
    int quad = (r >> 7) & 3;
    int nhi  = (r >> 9) & 15;
    int ks   = (r >> 13) & 1;
    int c    = (r >> 14) & 3;
    const float* W;
    switch (L) {
        case 0: W = xW1; break;
        case 1: W = xW2; break;
        case 2: W = xW3; break;
        case 3: W = tW1; break;
        case 4: W = tW2; break;
        default: W = tW3; break;
    }
    int n = nhi * 16 + ln;
    int k = c * 64 + ks * 32 + quad * 8 + j;
    dst[g] = (_Float16)W[k * 256 + n];
}

// ---------------------------------------------------------------------------
// Main fused kernel. Block = 256 threads (4 waves), tile = 64 rows.
// Wave w owns out-channels [w*64, w*64+64) in every 256->256 layer.
// ---------------------------------------------------------------------------

__device__ __forceinline__ void layer0_scalar(
    float xv, const float* __restrict__ W0, const float* __restrict__ b0,
    _Float16* __restrict__ hb, int tid)
{
    int m = tid >> 2;        // 64 rows, 4 threads per row
    int q = tid & 3;
#pragma unroll
    for (int g = 0; g < 8; ++g) {
        int n0 = g * 32 + q * 8;        // 4 q-addresses -> 4 distinct banks
        f16x8 hv;
#pragma unroll
        for (int e = 0; e < 8; ++e) {
            float z = fmaf(xv, W0[n0 + e], b0[n0 + e]);
            hv[e] = (_Float16)__sinf(z);
        }
        *(f16x8*)((char*)hb + hswz(m, n0 * 2)) = hv;
    }
}

// One GEMM phase: acc = Wl x rb (8 K-groups, 16 MFMA each) on the afr[2][4]
// depth-2 register pipeline (refill buf[g&1] for g+2 after last use; g=6/7
// load Wnext's g0/g1 -- stays in flight across the caller's raw barrier).
// MODE 1: slice the OTHER MLP's writeback sin(wacc+bias[LDS]) -> wb_lds,
//         2 of 16 fragments per g (R6-proven slicing).
// MODE 2: slice layer0_t, one 8-channel group per g -> wb_lds.
template<int MODE>   // 0 plain, 1 writeback, 2 layer0-slice
__device__ __forceinline__ void gemm_phase(
    const _Float16* __restrict__ Wl,
    const _Float16* __restrict__ Wnext,    // nullptr at the end
    const _Float16* __restrict__ rb,       // LDS read buffer (activations)
    f32x4 acc[4][4], f16x8 afr[2][4],
    f32x4 wacc[4][4],                      // MODE 1: prev phase's acc
    const float* __restrict__ wbias,       // MODE 1: LDS bias for wacc
    _Float16* __restrict__ wb_lds,         // MODE 1/2: LDS write target
    float xv,                              // MODE 2: scalar input
    const float* __restrict__ W0,          // MODE 2: LDS 1->256 weights
    const float* __restrict__ b0,          // MODE 2: LDS bias
    int tid, int lane, int ln, int quad, int wave)
{
    f32x4 zero = {0.f, 0.f, 0.f, 0.f};
#pragma unroll
    for (int i = 0; i < 4; ++i)
#pragma unroll
        for (int j = 0; j < 4; ++j)
            acc[i][j] = zero;

    const _Float16* abase = Wl + wave * 2048 + lane * 8;

#pragma unroll
    for (int g = 0; g < 8; ++g) {
        f16x8 bfr[4];
#pragma unroll
        for (int j = 0; j < 4; ++j)      // B: activations, all 64 rows
            bfr[j] = *(const f16x8*)((const char*)rb +
                                     hswz(16 * j + ln, g * 64 + quad * 16));

        __builtin_amdgcn_s_setprio(1);
#pragma unroll
        for (int i = 0; i < 4; ++i)
#pragma unroll
            for (int j = 0; j < 4; ++j)
                acc[i][j] = __builtin_amdgcn_mfma_f32_16x16x32_f16(
                    afr[g & 1][i], bfr[j], acc[i][j], 0, 0, 0);
        __builtin_amdgcn_s_setprio(0);

        // Refill buf[g&1] for g+2 (program-order after its last MFMA use).
        if (g < 6) {
#pragma unroll
            for (int i = 0; i < 4; ++i)
                afr[g & 1][i] = *(const f16x8*)(abase + (g + 2) * 8192 + i * 512);
        } else if (Wnext) {              // g=6 -> next g0 (buf0); g=7 -> g1 (buf1)
#pragma unroll
            for (int i = 0; i < 4; ++i)
                afr[g & 1][i] = *(const f16x8*)(Wnext + (g - 6) * 8192 +
                                                wave * 2048 + lane * 8 + i * 512);
        }

        if (MODE == 1) {                 // writeback slice: frag wi, 2 wj's
            const int wi = g >> 1;
            const int nb = wave * 64 + 16 * wi + quad * 4;
            f32x4 bv = *(const f32x4*)&wbias[nb];            // LDS, 4-addr bcast
#pragma unroll
            for (int jo = 0; jo < 2; ++jo) {
                const int wj = (g & 1) * 2 + jo;
                f16x4 hv;
                hv[0] = (_Float16)__sinf(wacc[wi][wj][0] + bv[0]);
                hv[1] = (_Float16)__sinf(wacc[wi][wj][1] + bv[1]);
                hv[2] = (_Float16)__sinf(wacc[wi][wj][2] + bv[2]);
                hv[3] = (_Float16)__sinf(wacc[wi][wj][3] + bv[3]);
                *(f16x4*)((char*)wb_lds + hswz(16 * wj + ln, nb * 2)) = hv;
            }
        } else if (MODE == 2) {          // layer0 slice: one 8-ch group
            const int m = tid >> 2, q = tid & 3;
            const int n0 = g * 32 + q * 8;
            f16x8 hv;
#pragma unroll
            for (int e = 0; e < 8; ++e) {
                float z = fmaf(xv, W0[n0 + e], b0[n0 + e]);
                hv[e] = (_Float16)__sinf(z);
            }
            *(f16x8*)((char*)wb_lds + hswz(m, n0 * 2)) = hv;
        }
    }
}

__global__ __launch_bounds__(256, 2)
void mlp_fused(const float* __restrict__ x,
               const float* __restrict__ xW0, const float* __restrict__ xb0,
               const float* __restrict__ xb1, const float* __restrict__ xb2,
               const float* __restrict__ xb3,
               const float* __restrict__ tW0, const float* __restrict__ tb0,
               const float* __restrict__ tb1, const float* __restrict__ tb2,
               const float* __restrict__ tb3,
               const _Float16* __restrict__ Wp,
               float* __restrict__ out)
{
    __shared__ __align__(16) _Float16 hbuf[2][64 * 256];   // [0]=x acts, [1]=t acts
    __shared__ __align__(16) float    params[10 * 256];    // 10 KB small params

    const int tid = threadIdx.x;
    const int lane = tid & 63;
    const int wave = tid >> 6;       // 0..3
    const int ln = lane & 15;
    const int quad = lane >> 4;
    const int row0 = blockIdx.x * 64;

    // Preload all small params to LDS.
    // segs: 0 xW0, 1 xb0, 2 tW0, 3 tb0, 4 xb1, 5 xb2, 6 xb3, 7 tb1, 8 tb2, 9 tb3
    {
        const float* psrc[10] = {xW0, xb0, tW0, tb0, xb1, xb2, xb3, tb1, tb2, tb3};
#pragma unroll
        for (int s = 0; s < 10; ++s)
            params[s * 256 + tid] = psrc[s][tid];
    }
    const float2 xv2 = ((const float2*)x)[row0 + (tid >> 2)];  // both MLP inputs

    f32x4 xacc[4][4], tacc[4][4];    // 128 AGPR
    f16x8 afr[2][4];                 // A-fragment register double-buffer (32 VGPR)

    // Prologue: xW1 g0 -> buf0, g1 -> buf1; land during layer0_x's sin work.
#pragma unroll
    for (int s = 0; s < 2; ++s)
#pragma unroll
        for (int i = 0; i < 4; ++i)
            afr[s][i] = *(const f16x8*)(Wp + s * 8192 + wave * 2048 +
                                        lane * 8 + i * 512);
    barrier_lds();                    // params visible to all waves

    // ----- layer0_x -----
    layer0_scalar(xv2.x, &params[0], &params[256], hbuf[0], tid);
    barrier_lds();                    // x acts visible

    // ----- 6 alternating GEMM phases -----
    // P1: x1; layer0_t sliced in -> hbuf[1]
    gemm_phase<2>(Wp + 0 * 65536, Wp + 3 * 65536, hbuf[0], xacc, afr,
                  nullptr, nullptr, hbuf[1],
                  xv2.y, &params[2 * 256], &params[3 * 256],
                  tid, lane, ln, quad, wave);
    barrier_lds();
    // P2: t1 || wb_x1 -> hbuf[0]
    gemm_phase<1>(Wp + 3 * 65536, Wp + 1 * 65536, hbuf[1], tacc, afr,
                  xacc, &params[4 * 256], hbuf[0],
                  0.f, nullptr, nullptr, tid, lane, ln, quad, wave);
    barrier_lds();
    // P3: x2 || wb_t1 -> hbuf[1]
    gemm_phase<1>(Wp + 1 * 65536, Wp + 4 * 65536, hbuf[0], xacc, afr,
                  tacc, &params[7 * 256], hbuf[1],
                  0.f, nullptr, nullptr, tid, lane, ln, quad, wave);
    barrier_lds();
    // P4: t2 || wb_x2 -> hbuf[0]
    gemm_phase<1>(Wp + 4 * 65536, Wp + 2 * 65536, hbuf[1], tacc, afr,
                  xacc, &params[5 * 256], hbuf[0],
                  0.f, nullptr, nullptr, tid, lane, ln, quad, wave);
    barrier_lds();
    // P5: x3 || wb_t2 -> hbuf[1]
    gemm_phase<1>(Wp + 2 * 65536, Wp + 5 * 65536, hbuf[0], xacc, afr,
                  tacc, &params[8 * 256], hbuf[1],
                  0.f, nullptr, nullptr, tid, lane, ln, quad, wave);
    barrier_lds();
    // P6: t3
    gemm_phase<0>(Wp + 5 * 65536, nullptr, hbuf[1], tacc, afr,
                  nullptr, nullptr, nullptr,
                  0.f, nullptr, nullptr, tid, lane, ln, quad, wave);

    // ----- combine: even/odd strided dot, fp32 -----
    const float* xb3l = &params[6 * 256];
    const float* tb3l = &params[9 * 256];
    float ev[4] = {0.f, 0.f, 0.f, 0.f};
    float od[4] = {0.f, 0.f, 0.f, 0.f};
#pragma unroll
    for (int i = 0; i < 4; ++i) {
        int nb = wave * 64 + 16 * i + quad * 4;
        f32x4 xb = *(const f32x4*)&xb3l[nb];
        f32x4 tb = *(const f32x4*)&tb3l[nb];
#pragma unroll
        for (int j = 0; j < 4; ++j) {
            float a0 = xacc[i][j][0] + xb[0], c0 = tacc[i][j][0] + tb[0];
            float a1 = xacc[i][j][1] + xb[1], c1 = tacc[i][j][1] + tb[1];
            float a2 = xacc[i][j][2] + xb[2], c2 = tacc[i][j][2] + tb[2];
            float a3 = xacc[i][j][3] + xb[3], c3 = tacc[i][j][3] + tb[3];
            ev[j] += a0 * c0 + a2 * c2;      // channel parity = reg index parity
            od[j] += a1 * c1 + a3 * c3;
        }
    }
#pragma unroll
    for (int j = 0; j < 4; ++j) {            // reduce over the 4 quads
        ev[j] += __shfl_xor(ev[j], 16, 64);
        ev[j] += __shfl_xor(ev[j], 32, 64);
        od[j] += __shfl_xor(od[j], 16, 64);
        od[j] += __shfl_xor(od[j], 32, 64);
    }

    // hbuf[0] dead: its last readers (P5) all passed the P5->P6 barrier.
    float* red = (float*)hbuf[0];
    if (lane < 16) {
#pragma unroll
        for (int j = 0; j < 4; ++j) {
            red[wave * 128 + j * 32 + lane * 2 + 0] = ev[j];
            red[wave * 128 + j * 32 + lane * 2 + 1] = od[j];
        }
    }
    __syncthreads();
    if (tid < 128) {                         // sum the 4 wave partials; coalesced store
        int jj = tid >> 5, m16 = (tid >> 1) & 15, p = tid & 1;
        int base = jj * 32 + m16 * 2 + p;
        float s = red[base] + red[128 + base] + red[256 + base] + red[384 + base];
        out[(row0 + 16 * jj + m16) * 2 + p] = s;
    }
}

// ---------------------------------------------------------------------------
extern "C" void kernel_launch(void* const* d_in, const int* in_sizes, int n_in,
                              void* d_out, int out_size, void* d_ws, size_t ws_size,
                              hipStream_t stream)
{
    const float* x   = (const float*)d_in[0];
    const float* xW0 = (const float*)d_in[1];
    const float* xb0 = (const float*)d_in[2];
    const float* xW1 = (const float*)d_in[3];
    const float* xb1 = (const float*)d_in[4];
    const float* xW2 = (const float*)d_in[5];
    const float* xb2 = (const float*)d_in[6];
    const float* xW3 = (const float*)d_in[7];
    const float* xb3 = (const float*)d_in[8];
    const float* tW0 = (const float*)d_in[9];
    const float* tb0 = (const float*)d_in[10];
    const float* tW1 = (const float*)d_in[11];
    const float* tb1 = (const float*)d_in[12];
    const float* tW2 = (const float*)d_in[13];
    const float* tb2 = (const float*)d_in[14];
    const float* tW3 = (const float*)d_in[15];
    const float* tb3 = (const float*)d_in[16];

    _Float16* Wp = (_Float16*)d_ws;          // 6*65536 fp16 = 768 KB
    const int N = in_sizes[0] / 2;           // 1,000,000 (divisible by 64)

    prepack<<<1536, 256, 0, stream>>>(xW1, xW2, xW3, tW1, tW2, tW3, Wp);
    mlp_fused<<<N / 64, 256, 0, stream>>>(x, xW0, xb0, xb1, xb2, xb3,
                                          tW0, tb0, tb1, tb2, tb3,
                                          Wp, (float*)d_out);
}

// Round 11
// 808.269 us; speedup vs baseline: 1.6823x; 1.0581x over previous
//
#include <hip/hip_runtime.h>

// SP_DNN: two fused 1->256->256->256->256 MLPs (sin activations) + strided rowwise dot.
// fp16 MFMA (16x16x32), fp32 accumulate.
//
// R11 = R10 (855us, MfmaUtil 51.5%) + B-operand double-buffer -- the last
// depth-0 input stream. R10's per-g pattern was: 4 ds_read_b128 (bfr) ->
// lgkm wait -> 16 MFMA; the ~120-200cyc LDS latency was exposed every g
// (A is depth-2 prefetched, wb is in-shadow; B was fetched at distance 0).
// Now bfr[2][4]: iter g issues g+1's reads into buf[(g+1)&1] BEFORE the
// MFMA cluster consumes buf[g&1] (whose reads were issued a full iteration
// ~150+cyc earlier); compiler emits counted lgkm waits (4 newer pending).
// WAR-safe by parity. +16 VGPR: 116+128 AGPR = 244 <= 256 (2 blk/CU).
// Phase structure unchanged: 6 alternating x/t GEMM phases, other MLP's
// writeback + layer0_t sliced into the MFMA shadow, depth-2 A-prefetch
// chaining across phases, lgkm-only barriers, params in LDS.

typedef _Float16 f16x8 __attribute__((ext_vector_type(8)));
typedef _Float16 f16x4 __attribute__((ext_vector_type(4)));
typedef float f32x4 __attribute__((ext_vector_type(4)));

// Swizzled act-buffer byte offset: row m (0..63, 512 B stride), kbyte in
// [0,512). 16B unit index XORed with (m&7): any 8-lane chunk of a B-read
// covers all 32 banks exactly once; writeback/layer0 <=2-way (free).
__device__ __forceinline__ int hswz(int m, int kbyte) {
    return m * 512 + ((((kbyte >> 4) ^ (m & 7)) & 31) << 4) + (kbyte & 15);
}

// Raw workgroup barrier draining LDS ops only; global loads stay in flight.
__device__ __forceinline__ void barrier_lds() {
    asm volatile("s_waitcnt lgkmcnt(0)" ::: "memory");
    __builtin_amdgcn_s_barrier();
}

// ---------------------------------------------------------------------------
// Prepack: 6 matrices W[k][n] (256x256 f32, k-major) -> fp16 A-fragment-major:
// idx = ((((c*2+ks)*16 + nhi)*4 + quad)*16 + ln)*8 + j
//   n = nhi*16+ln, k = c*64 + ks*32 + quad*8 + j
// ---------------------------------------------------------------------------
__global__ void prepack(const float* __restrict__ xW1, const float* __restrict__ xW2,
                        const float* __restrict__ xW3, const float* __restrict__ tW1,
                        const float* __restrict__ tW2, const float* __restrict__ tW3,
                        _Float16* __restrict__ dst)
{
    int g = blockIdx.x * 256 + threadIdx.x;   // 6*65536 threads exactly
    int L = g >> 16;
    int r = g & 65535;
    int j    = r & 7;
    int ln   = (r >> 3) & 15;
    int quad = (r >> 7) & 3;
    int nhi  = (r >> 9) & 15;
    int ks   = (r >> 13) & 1;
    int c    = (r >> 14) & 3;
    const float* W;
    switch (L) {
        case 0: W = xW1; break;
        case 1: W = xW2; break;
        case 2: W = xW3; break;
        case 3: W = tW1; break;
        case 4: W = tW2; break;
        default: W = tW3; break;
    }
    int n = nhi * 16 + ln;
    int k = c * 64 + ks * 32 + quad * 8 + j;
    dst[g] = (_Float16)W[k * 256 + n];
}

// ---------------------------------------------------------------------------
// Main fused kernel. Block = 256 threads (4 waves), tile = 64 rows.
// Wave w owns out-channels [w*64, w*64+64) in every 256->256 layer.
// ---------------------------------------------------------------------------

__device__ __forceinline__ void layer0_scalar(
    float xv, const float* __restrict__ W0, const float* __restrict__ b0,
    _Float16* __restrict__ hb, int tid)
{
    int m = tid >> 2;        // 64 rows, 4 threads per row
    int q = tid & 3;
#pragma unroll
    for (int g = 0; g < 8; ++g) {
        int n0 = g * 32 + q * 8;        // 4 q-addresses -> 4 distinct banks
        f16x8 hv;
#pragma unroll
        for (int e = 0; e < 8; ++e) {
            float z = fmaf(xv, W0[n0 + e], b0[n0 + e]);
            hv[e] = (_Float16)__sinf(z);
        }
        *(f16x8*)((char*)hb + hswz(m, n0 * 2)) = hv;
    }
}

// One GEMM phase: acc = Wl x rb (8 K-groups, 16 MFMA each).
// A: afr[2][4] depth-2 register pipeline (refill buf[g&1] for g+2 after
//    last use; g=6/7 load Wnext's g0/g1, staying in flight across barriers).
// B: bfr[2][4] depth-1 LDS pipeline (issue g+1's ds_reads before g's MFMAs).
// MODE 1: slice the OTHER MLP's writeback sin(wacc+bias[LDS]) -> wb_lds,
//         2 of 16 fragments per g. MODE 2: slice layer0_t, 1 group per g.
template<int MODE>   // 0 plain, 1 writeback, 2 layer0-slice
__device__ __forceinline__ void gemm_phase(
    const _Float16* __restrict__ Wl,
    const _Float16* __restrict__ Wnext,    // nullptr at the end
    const _Float16* __restrict__ rb,       // LDS read buffer (activations)
    f32x4 acc[4][4], f16x8 afr[2][4],
    f32x4 wacc[4][4],                      // MODE 1: prev phase's acc
    const float* __restrict__ wbias,       // MODE 1: LDS bias for wacc
    _Float16* __restrict__ wb_lds,         // MODE 1/2: LDS write target
    float xv,                              // MODE 2: scalar input
    const float* __restrict__ W0,          // MODE 2: LDS 1->256 weights
    const float* __restrict__ b0,          // MODE 2: LDS bias
    int tid, int lane, int ln, int quad, int wave)
{
    f32x4 zero = {0.f, 0.f, 0.f, 0.f};
#pragma unroll
    for (int i = 0; i < 4; ++i)
#pragma unroll
        for (int j = 0; j < 4; ++j)
            acc[i][j] = zero;

    const _Float16* abase = Wl + wave * 2048 + lane * 8;

    f16x8 bfr[2][4];
#pragma unroll
    for (int j = 0; j < 4; ++j)          // B prologue: g0 -> buf0
        bfr[0][j] = *(const f16x8*)((const char*)rb +
                                    hswz(16 * j + ln, quad * 16));

#pragma unroll
    for (int g = 0; g < 8; ++g) {
        if (g < 7) {                     // issue g+1's B reads before g's MFMAs
#pragma unroll
            for (int j = 0; j < 4; ++j)
                bfr[(g + 1) & 1][j] = *(const f16x8*)((const char*)rb +
                                 hswz(16 * j + ln, (g + 1) * 64 + quad * 16));
        }

        __builtin_amdgcn_s_setprio(1);
#pragma unroll
        for (int i = 0; i < 4; ++i)
#pragma unroll
            for (int j = 0; j < 4; ++j)
                acc[i][j] = __builtin_amdgcn_mfma_f32_16x16x32_f16(
                    afr[g & 1][i], bfr[g & 1][j], acc[i][j], 0, 0, 0);
        __builtin_amdgcn_s_setprio(0);

        // Refill A buf[g&1] for g+2 (program-order after its last MFMA use).
        if (g < 6) {
#pragma unroll
            for (int i = 0; i < 4; ++i)
                afr[g & 1][i] = *(const f16x8*)(abase + (g + 2) * 8192 + i * 512);
        } else if (Wnext) {              // g=6 -> next g0 (buf0); g=7 -> g1 (buf1)
#pragma unroll
            for (int i = 0; i < 4; ++i)
                afr[g & 1][i] = *(const f16x8*)(Wnext + (g - 6) * 8192 +
                                                wave * 2048 + lane * 8 + i * 512);
        }

        if (MODE == 1) {                 // writeback slice: frag wi, 2 wj's
            const int wi = g >> 1;
            const int nb = wave * 64 + 16 * wi + quad * 4;
            f32x4 bv = *(const f32x4*)&wbias[nb];            // LDS, 4-addr bcast
#pragma unroll
            for (int jo = 0; jo < 2; ++jo) {
                const int wj = (g & 1) * 2 + jo;
                f16x4 hv;
                hv[0] = (_Float16)__sinf(wacc[wi][wj][0] + bv[0]);
                hv[1] = (_Float16)__sinf(wacc[wi][wj][1] + bv[1]);
                hv[2] = (_Float16)__sinf(wacc[wi][wj][2] + bv[2]);
                hv[3] = (_Float16)__sinf(wacc[wi][wj][3] + bv[3]);
                *(f16x4*)((char*)wb_lds + hswz(16 * wj + ln, nb * 2)) = hv;
            }
        } else if (MODE == 2) {          // layer0 slice: one 8-ch group
            const int m = tid >> 2, q = tid & 3;
            const int n0 = g * 32 + q * 8;
            f16x8 hv;
#pragma unroll
            for (int e = 0; e < 8; ++e) {
                float z = fmaf(xv, W0[n0 + e], b0[n0 + e]);
                hv[e] = (_Float16)__sinf(z);
            }
            *(f16x8*)((char*)wb_lds + hswz(m, n0 * 2)) = hv;
        }
    }
}

__global__ __launch_bounds__(256, 2)
void mlp_fused(const float* __restrict__ x,
               const float* __restrict__ xW0, const float* __restrict__ xb0,
               const float* __restrict__ xb1, const float* __restrict__ xb2,
               const float* __restrict__ xb3,
               const float* __restrict__ tW0, const float* __restrict__ tb0,
               const float* __restrict__ tb1, const float* __restrict__ tb2,
               const float* __restrict__ tb3,
               const _Float16* __restrict__ Wp,
               float* __restrict__ out)
{
    __shared__ __align__(16) _Float16 hbuf[2][64 * 256];   // [0]=x acts, [1]=t acts
    __shared__ __align__(16) float    params[10 * 256];    // 10 KB small params

    const int tid = threadIdx.x;
    const int lane = tid & 63;
    const int wave = tid >> 6;       // 0..3
    const int ln = lane & 15;
    const int quad = lane >> 4;
    const int row0 = blockIdx.x * 64;

    // Preload all small params to LDS.
    // segs: 0 xW0, 1 xb0, 2 tW0, 3 tb0, 4 xb1, 5 xb2, 6 xb3, 7 tb1, 8 tb2, 9 tb3
    {
        const float* psrc[10] = {xW0, xb0, tW0, tb0, xb1, xb2, xb3, tb1, tb2, tb3};
#pragma unroll
        for (int s = 0; s < 10; ++s)
            params[s * 256 + tid] = psrc[s][tid];
    }
    const float2 xv2 = ((const float2*)x)[row0 + (tid >> 2)];  // both MLP inputs

    f32x4 xacc[4][4], tacc[4][4];    // 128 AGPR
    f16x8 afr[2][4];                 // A-fragment register double-buffer (32 VGPR)

    // Prologue: xW1 g0 -> buf0, g1 -> buf1; land during layer0_x's sin work.
#pragma unroll
    for (int s = 0; s < 2; ++s)
#pragma unroll
        for (int i = 0; i < 4; ++i)
            afr[s][i] = *(const f16x8*)(Wp + s * 8192 + wave * 2048 +
                                        lane * 8 + i * 512);
    barrier_lds();                    // params visible to all waves

    // ----- layer0_x -----
    layer0_scalar(xv2.x, &params[0], &params[256], hbuf[0], tid);
    barrier_lds();                    // x acts visible

    // ----- 6 alternating GEMM phases -----
    // P1: x1; layer0_t sliced in -> hbuf[1]
    gemm_phase<2>(Wp + 0 * 65536, Wp + 3 * 65536, hbuf[0], xacc, afr,
                  nullptr, nullptr, hbuf[1],
                  xv2.y, &params[2 * 256], &params[3 * 256],
                  tid, lane, ln, quad, wave);
    barrier_lds();
    // P2: t1 || wb_x1 -> hbuf[0]
    gemm_phase<1>(Wp + 3 * 65536, Wp + 1 * 65536, hbuf[1], tacc, afr,
                  xacc, &params[4 * 256], hbuf[0],
                  0.f, nullptr, nullptr, tid, lane, ln, quad, wave);
    barrier_lds();
    // P3: x2 || wb_t1 -> hbuf[1]
    gemm_phase<1>(Wp + 1 * 65536, Wp + 4 * 65536, hbuf[0], xacc, afr,
                  tacc, &params[7 * 256], hbuf[1],
                  0.f, nullptr, nullptr, tid, lane, ln, quad, wave);
    barrier_lds();
    // P4: t2 || wb_x2 -> hbuf[0]
    gemm_phase<1>(Wp + 4 * 65536, Wp + 2 * 65536, hbuf[1], tacc, afr,
                  xacc, &params[5 * 256], hbuf[0],
                  0.f, nullptr, nullptr, tid, lane, ln, quad, wave);
    barrier_lds();
    // P5: x3 || wb_t2 -> hbuf[1]
    gemm_phase<1>(Wp + 2 * 65536, Wp + 5 * 65536, hbuf[0], xacc, afr,
                  tacc, &params[8 * 256], hbuf[1],
                  0.f, nullptr, nullptr, tid, lane, ln, quad, wave);
    barrier_lds();
    // P6: t3
    gemm_phase<0>(Wp + 5 * 65536, nullptr, hbuf[1], tacc, afr,
                  nullptr, nullptr, nullptr,
                  0.f, nullptr, nullptr, tid, lane, ln, quad, wave);

    // ----- combine: even/odd strided dot, fp32 -----
    const float* xb3l = &params[6 * 256];
    const float* tb3l = &params[9 * 256];
    float ev[4] = {0.f, 0.f, 0.f, 0.f};
    float od[4] = {0.f, 0.f, 0.f, 0.f};
#pragma unroll
    for (int i = 0; i < 4; ++i) {
        int nb = wave * 64 + 16 * i + quad * 4;
        f32x4 xb = *(const f32x4*)&xb3l[nb];
        f32x4 tb = *(const f32x4*)&tb3l[nb];
#pragma unroll
        for (int j = 0; j < 4; ++j) {
            float a0 = xacc[i][j][0] + xb[0], c0 = tacc[i][j][0] + tb[0];
            float a1 = xacc[i][j][1] + xb[1], c1 = tacc[i][j][1] + tb[1];
            float a2 = xacc[i][j][2] + xb[2], c2 = tacc[i][j][2] + tb[2];
            float a3 = xacc[i][j][3] + xb[3], c3 = tacc[i][j][3] + tb[3];
            ev[j] += a0 * c0 + a2 * c2;      // channel parity = reg index parity
            od[j] += a1 * c1 + a3 * c3;
        }
    }
#pragma unroll
    for (int j = 0; j < 4; ++j) {            // reduce over the 4 quads
        ev[j] += __shfl_xor(ev[j], 16, 64);
        ev[j] += __shfl_xor(ev[j], 32, 64);
        od[j] += __shfl_xor(od[j], 16, 64);
        od[j] += __shfl_xor(od[j], 32, 64);
    }

    // hbuf[0] dead: its last readers (P5) all passed the P5->P6 barrier.
    float* red = (float*)hbuf[0];
    if (lane < 16) {
#pragma unroll
        for (int j = 0; j < 4; ++j) {
            red[wave * 128 + j * 32 + lane * 2 + 0] = ev[j];
            red[wave * 128 + j * 32 + lane * 2 + 1] = od[j];
        }
    }
    __syncthreads();
    if (tid < 128) {                         // sum the 4 wave partials; coalesced store
        int jj = tid >> 5, m16 = (tid >> 1) & 15, p = tid & 1;
        int base = jj * 32 + m16 * 2 + p;
        float s = red[base] + red[128 + base] + red[256 + base] + red[384 + base];
        out[(row0 + 16 * jj + m16) * 2 + p] = s;
    }
}

// ---------------------------------------------------------------------------
extern "C" void kernel_launch(void* const* d_in, const int* in_sizes, int n_in,
                              void* d_out, int out_size, void* d_ws, size_t ws_size,
                              hipStream_t stream)
{
    const float* x   = (const float*)d_in[0];
    const float* xW0 = (const float*)d_in[1];
    const float* xb0 = (const float*)d_in[2];
    const float* xW1 = (const float*)d_in[3];
    const float* xb1 = (const float*)d_in[4];
    const float* xW2 = (const float*)d_in[5];
    const float* xb2 = (const float*)d_in[6];
    const float* xW3 = (const float*)d_in[7];
    const float* xb3 = (const float*)d_in[8];
    const float* tW0 = (const float*)d_in[9];
    const float* tb0 = (const float*)d_in[10];
    const float* tW1 = (const float*)d_in[11];
    const float* tb1 = (const float*)d_in[12];
    const float* tW2 = (const float*)d_in[13];
    const float* tb2 = (const float*)d_in[14];
    const float* tW3 = (const float*)d_in[15];
    const float* tb3 = (const float*)d_in[16];

    _Float16* Wp = (_Float16*)d_ws;          // 6*65536 fp16 = 768 KB
    const int N = in_sizes[0] / 2;           // 1,000,000 (divisible by 64)

    prepack<<<1536, 256, 0, stream>>>(xW1, xW2, xW3, tW1, tW2, tW3, Wp);
    mlp_fused<<<N / 64, 256, 0, stream>>>(x, xW0, xb0, xb1, xb2, xb3,
                                          tW0, tb0, tb1, tb2, tb3,
                                          Wp, (float*)d_out);
}